// Round 6
// baseline (450.928 us; speedup 1.0000x reference)
//
#include <hip/hip_runtime.h>
#include <hip/hip_bf16.h>
#include <cstdint>

#define NEG_SLOPE 0.2f

typedef __attribute__((ext_vector_type(8))) short bf16x8;
typedef __attribute__((ext_vector_type(4))) float f32x4;

__device__ __forceinline__ float bf2f(uint32_t u) {
  union { float f; uint32_t i; } v;
  v.i = u << 16;
  return v.f;
}
__device__ __forceinline__ float lo16(uint32_t u) {
  union { float f; uint32_t i; } v;
  v.i = u << 16;
  return v.f;
}
__device__ __forceinline__ float hi16(uint32_t u) {
  union { float f; uint32_t i; } v;
  v.i = u & 0xffff0000u;
  return v.f;
}
__device__ __forceinline__ ushort f2bf(float f) {
  union { float f; uint32_t i; } v;
  v.f = f;
  uint32_t r = v.i + 0x7FFF + ((v.i >> 16) & 1);  // round-nearest-even
  return (ushort)(r >> 16);
}

// ---------------------------------------------------------------------------
// prep: cast x -> bf16, transpose+cast W1/W2/W3, CSR count pass,
// and fold attention vectors through W1:  at_s[k][h] = sum_c W1[k][h*64+c]*a1s[h][c]
// ---------------------------------------------------------------------------
__global__ void prep_kernel(const float4* __restrict__ x,
                            uint2* __restrict__ x_bf, int n_x4,
                            const float* __restrict__ W1,
                            ushort* __restrict__ W1T,
                            const float* __restrict__ W2,
                            ushort* __restrict__ W2T,
                            const float* __restrict__ W3,
                            ushort* __restrict__ W3T,
                            const int* __restrict__ dst, int* __restrict__ cnt,
                            const float* __restrict__ a1s,
                            const float* __restrict__ a1d,
                            float* __restrict__ at_s, float* __restrict__ at_d,
                            int E) {
  int i = blockIdx.x * 256 + threadIdx.x;
  const int r0 = n_x4;
  const int r1 = r0 + 512 * 128;
  const int r2 = r1 + 64 * 512;
  const int r3 = r2 + 64 * 64;
  const int r4 = r3 + E;
  const int r5 = r4 + 1024;
  const int r6 = r5 + 1024;
  if (i < r0) {
    float4 v = x[i];
    uint2 o;
    o.x = (uint32_t)f2bf(v.x) | ((uint32_t)f2bf(v.y) << 16);
    o.y = (uint32_t)f2bf(v.z) | ((uint32_t)f2bf(v.w) << 16);
    x_bf[i] = o;
  } else if (i < r1) {
    int idx = i - r0;
    int n = idx >> 7, k = idx & 127;
    W1T[idx] = f2bf(W1[(size_t)k * 512 + n]);
  } else if (i < r2) {
    int idx = i - r1;
    int n = idx >> 9, k = idx & 511;
    W2T[idx] = f2bf(W2[(size_t)k * 64 + n]);
  } else if (i < r3) {
    int idx = i - r2;
    int n = idx >> 6, k = idx & 63;
    W3T[idx] = f2bf(W3[(size_t)k * 64 + n]);
  } else if (i < r4) {
    atomicAdd(&cnt[dst[i - r3]], 1);
  } else if (i < r5) {
    int idx = i - r4;  // k*8 + h
    int k = idx >> 3, h = idx & 7;
    float a = 0.f;
    for (int c = 0; c < 64; ++c)
      a = fmaf(W1[(size_t)k * 512 + h * 64 + c], a1s[h * 64 + c], a);
    at_s[idx] = a;
  } else if (i < r6) {
    int idx = i - r5;
    int k = idx >> 3, h = idx & 7;
    float a = 0.f;
    for (int c = 0; c < 64; ++c)
      a = fmaf(W1[(size_t)k * 512 + h * 64 + c], a1d[h * 64 + c], a);
    at_d[idx] = a;
  }
}

// ---------------------------------------------------------------------------
// Layer-1 al from x directly: al_s[n][h] = x[n] . at_s[:,h]  (K=128, 16 outs)
// ---------------------------------------------------------------------------
__global__ __launch_bounds__(256) void algemm_kernel(
    const ushort* __restrict__ x_bf, const float* __restrict__ at_s,
    const float* __restrict__ at_d, float* __restrict__ al_s,
    float* __restrict__ al_d, int Nn) {
  const int n = blockIdx.x * 256 + threadIdx.x;
  if (n >= Nn) return;
  float as8[8] = {}, ad8[8] = {};
  const ushort* xp = x_bf + (size_t)n * 128;
  for (int k0 = 0; k0 < 128; k0 += 8) {
    const uint4 xw = *(const uint4*)(xp + k0);
    const uint32_t ww0 = xw.x, ww1 = xw.y, ww2 = xw.z, ww3 = xw.w;
    float xv[8];
    xv[0] = lo16(ww0); xv[1] = hi16(ww0);
    xv[2] = lo16(ww1); xv[3] = hi16(ww1);
    xv[4] = lo16(ww2); xv[5] = hi16(ww2);
    xv[6] = lo16(ww3); xv[7] = hi16(ww3);
#pragma unroll
    for (int t = 0; t < 8; ++t) {
      const int k = k0 + t;
#pragma unroll
      for (int h = 0; h < 8; ++h) {
        as8[h] = fmaf(xv[t], at_s[k * 8 + h], as8[h]);
        ad8[h] = fmaf(xv[t], at_d[k * 8 + h], ad8[h]);
      }
    }
  }
  float4* ps = (float4*)(al_s + (size_t)n * 8);
  ps[0] = make_float4(as8[0], as8[1], as8[2], as8[3]);
  ps[1] = make_float4(as8[4], as8[5], as8[6], as8[7]);
  float4* pd = (float4*)(al_d + (size_t)n * 8);
  pd[0] = make_float4(ad8[0], ad8[1], ad8[2], ad8[3]);
  pd[1] = make_float4(ad8[4], ad8[5], ad8[6], ad8[7]);
}

// ---------------------------------------------------------------------------
// GEMM (N=64) + fused al (H=1): C[M,64] = A[M,K] @ BT[64,K].  (layer 3)
// ---------------------------------------------------------------------------
__global__ __launch_bounds__(256) void gemm_n64_al(
    const ushort* __restrict__ A, const ushort* __restrict__ BT,
    ushort* __restrict__ C, const float* __restrict__ asrc,
    const float* __restrict__ adst, float* __restrict__ al_s,
    float* __restrict__ al_d, int M, int K) {
  const int wave = threadIdx.x >> 6;
  const int lane = threadIdx.x & 63;
  const int rt = blockIdx.y * 4 + wave;
  const int r0 = rt * 16;
  if (r0 >= M) return;
  const int l15 = lane & 15, q = lane >> 4;
  const ushort* Ap = A + (size_t)(r0 + l15) * K + q * 8;
  f32x4 acc[4] = {};
  for (int k0 = 0; k0 < K; k0 += 32) {
    bf16x8 a = *(const bf16x8*)(Ap + k0);
#pragma unroll
    for (int j = 0; j < 4; ++j) {
      const bf16x8 b =
          *(const bf16x8*)(BT + (size_t)(j * 16 + l15) * K + q * 8 + k0);
      acc[j] = __builtin_amdgcn_mfma_f32_16x16x32_bf16(a, b, acc[j], 0, 0, 0);
    }
  }
#pragma unroll
  for (int j = 0; j < 4; ++j)
#pragma unroll
    for (int r = 0; r < 4; ++r) {
      int row = r0 + q * 4 + r;
      C[(size_t)row * 64 + j * 16 + l15] = f2bf(acc[j][r]);
    }
  float als_p[4] = {0.f, 0.f, 0.f, 0.f};
  float ald_p[4] = {0.f, 0.f, 0.f, 0.f};
#pragma unroll
  for (int j = 0; j < 4; ++j) {
    float wsc = asrc[j * 16 + l15];
    float wdc = adst[j * 16 + l15];
#pragma unroll
    for (int r = 0; r < 4; ++r) {
      als_p[r] = fmaf(acc[j][r], wsc, als_p[r]);
      ald_p[r] = fmaf(acc[j][r], wdc, ald_p[r]);
    }
  }
#pragma unroll
  for (int r = 0; r < 4; ++r) {
    float vs = als_p[r], vd = ald_p[r];
#pragma unroll
    for (int off = 1; off < 16; off <<= 1) {
      vs += __shfl_xor(vs, off);
      vd += __shfl_xor(vd, off);
    }
    if (l15 == 0) {
      int row = r0 + q * 4 + r;
      al_s[row] = vs;
      al_d[row] = vd;
    }
  }
}

// ---------------------------------------------------------------------------
// FUSED layers 1b+2a: per 16-row tile:
//  stage 1: out1_tile[16][512] = ELU(agg_tile @ W1 (per-head) + b1) -> LDS
//  stage 2: h2_tile[16][64] = out1_tile @ W2T (K=512), + fused al2.
// agg is HEAD-MAJOR [8][N][128]: a head's 16-row A-tile is 4 KB contiguous
// (16 consecutive 256 B rows) -> dense 64 B segments at 256 B stride instead
// of the previous 2 KB-stride scatter that saturated the memory queues.
// ---------------------------------------------------------------------------
__global__ __launch_bounds__(256) void gemm12_kernel(
    const ushort* __restrict__ agg, const ushort* __restrict__ W1T,
    const float* __restrict__ b1, const ushort* __restrict__ W2T,
    const float* __restrict__ a2s, const float* __restrict__ a2d,
    ushort* __restrict__ h2, float* __restrict__ al_s,
    float* __restrict__ al_d, int M) {
  __shared__ ushort o1t[16][520];  // padded stride: 16B-aligned rows
  __shared__ float als_sm[4][16];
  __shared__ float ald_sm[4][16];
  const int w = threadIdx.x >> 6;
  const int lane = threadIdx.x & 63;
  const int l15 = lane & 15, q = lane >> 4;
  const int r0 = blockIdx.x * 16;
  const int rrd = min(r0 + l15, M - 1);  // clamped read row

  // ---- stage 1: two heads per wave
#pragma unroll
  for (int hi = 0; hi < 2; ++hi) {
    const int hd = w * 2 + hi;
    const ushort* Ap = agg + ((size_t)hd * M + rrd) * 128 + q * 8;
    f32x4 acc[4] = {};
    for (int k0 = 0; k0 < 128; k0 += 32) {
      bf16x8 a = *(const bf16x8*)(Ap + k0);
#pragma unroll
      for (int j = 0; j < 4; ++j) {
        const bf16x8 b = *(const bf16x8*)(W1T +
            (size_t)(hd * 64 + j * 16 + l15) * 128 + q * 8 + k0);
        acc[j] = __builtin_amdgcn_mfma_f32_16x16x32_bf16(a, b, acc[j], 0, 0, 0);
      }
    }
#pragma unroll
    for (int j = 0; j < 4; ++j)
#pragma unroll
      for (int r = 0; r < 4; ++r) {
        const int row = q * 4 + r;
        const int col = hd * 64 + j * 16 + l15;
        float v = acc[j][r] + b1[col];
        v = (v > 0.f) ? v : __expf(v) - 1.f;
        o1t[row][col] = f2bf(v);
      }
  }
  __syncthreads();

  // ---- stage 2: wave w computes h2 cols w*16..w*16+15, K=512 from LDS
  f32x4 acc2 = {};
  for (int k0 = 0; k0 < 512; k0 += 32) {
    const bf16x8 a = *(const bf16x8*)(&o1t[l15][k0 + q * 8]);
    const bf16x8 b = *(const bf16x8*)(W2T +
        (size_t)(w * 16 + l15) * 512 + q * 8 + k0);
    acc2 = __builtin_amdgcn_mfma_f32_16x16x32_bf16(a, b, acc2, 0, 0, 0);
  }
  const float wsc = a2s[w * 16 + l15];
  const float wdc = a2d[w * 16 + l15];
#pragma unroll
  for (int r = 0; r < 4; ++r) {
    const int row = r0 + q * 4 + r;
    if (row < M) h2[(size_t)row * 64 + w * 16 + l15] = f2bf(acc2[r]);
    float vs = acc2[r] * wsc, vd = acc2[r] * wdc;
#pragma unroll
    for (int off = 1; off < 16; off <<= 1) {
      vs += __shfl_xor(vs, off);
      vd += __shfl_xor(vd, off);
    }
    if (l15 == 0) {
      als_sm[w][q * 4 + r] = vs;
      ald_sm[w][q * 4 + r] = vd;
    }
  }
  __syncthreads();
  if (threadIdx.x < 16) {
    const int row = r0 + threadIdx.x;
    if (row < M) {
      const int t = threadIdx.x;
      al_s[row] = als_sm[0][t] + als_sm[1][t] + als_sm[2][t] + als_sm[3][t];
      al_d[row] = ald_sm[0][t] + ald_sm[1][t] + ald_sm[2][t] + ald_sm[3][t];
    }
  }
}

// ---------------------------------------------------------------------------
// CSR: per-block inclusive scan (block sums to bsum)
// ---------------------------------------------------------------------------
__global__ void scan_block(const int* __restrict__ in, int* __restrict__ out,
                           int* __restrict__ bsum, int n) {
  __shared__ int sm[256];
  int gid = blockIdx.x * 256 + threadIdx.x;
  int v = (gid < n) ? in[gid] : 0;
  sm[threadIdx.x] = v;
  __syncthreads();
  for (int off = 1; off < 256; off <<= 1) {
    int t = (threadIdx.x >= off) ? sm[threadIdx.x - off] : 0;
    __syncthreads();
    sm[threadIdx.x] += t;
    __syncthreads();
  }
  if (gid < n) out[gid] = sm[threadIdx.x];
  if (threadIdx.x == 255) bsum[blockIdx.x] = sm[255];
}

__global__ void scan_final2(const int* __restrict__ inc,
                            const int* __restrict__ bsum,
                            int* __restrict__ indptr, int* __restrict__ fill,
                            int n) {
  __shared__ int sm[256];
  const int t = threadIdx.x, bx = blockIdx.x;
  sm[t] = (t < bx) ? bsum[t] : 0;  // gridDim <= 256
  __syncthreads();
  for (int off = 128; off; off >>= 1) {
    if (t < off) sm[t] += sm[t + off];
    __syncthreads();
  }
  const int prefix = sm[0];
  int gid = bx * 256 + t;
  if (gid < n) {
    int val = inc[gid] + prefix;
    indptr[gid + 1] = val;
    fill[gid + 1] = val;
  }
  if (gid == 0) {
    indptr[0] = 0;
    fill[0] = 0;
  }
}

__global__ void scatter_kernel(const int* __restrict__ src,
                               const int* __restrict__ dst,
                               int* __restrict__ fill,
                               int* __restrict__ csr_src, int E) {
  int e = blockIdx.x * 256 + threadIdx.x;
  if (e < E) {
    int pos = atomicAdd(&fill[dst[e]], 1);
    csr_src[pos] = src[e];
  }
}

// ---------------------------------------------------------------------------
// Layer-1 attention in x-space, cooperative-row layout + 8-edge batched loads.
// Output agg is HEAD-MAJOR [8][N][128].
// ---------------------------------------------------------------------------
__global__ __launch_bounds__(256) void attn1x_kernel(
    const int* __restrict__ indptr, const int* __restrict__ csr_src,
    const float* __restrict__ al_s, const float* __restrict__ al_d,
    const ushort* __restrict__ x_bf, ushort* __restrict__ agg, int Nn) {
  __shared__ float u_sm[4][64 * 8];
  __shared__ int s_sm[4][64];
  const int wv = threadIdx.x >> 6;
  const int l = threadIdx.x & 63;
  const int w = (blockIdx.x * 256 + threadIdx.x) >> 6;
  if (w >= Nn) return;
  const int d = w;
  const int start = indptr[d];
  const int deg = indptr[d + 1] - start;
  const int total = deg + 1;  // + self loop
  const float4 ad0 = *(const float4*)(al_d + (size_t)d * 8);
  const float4 ad1 = *(const float4*)(al_d + (size_t)d * 8 + 4);
  const ushort* xcol = x_bf + l * 2;  // channel pair (2l, 2l+1)

  float acc0[8] = {};  // per-head accum, ch 2l
  float acc1[8] = {};  // per-head accum, ch 2l+1
  float den8[8] = {};
  float* usm = u_sm[wv];
  int* ssm = s_sm[wv];

  for (int e0 = 0; e0 < total; e0 += 64) {
    // ---- stage A: lane-parallel (s, u[8]) for this 64-edge block
    const int e = e0 + l;
    int s_l = d;
    float u8[8] = {};
    if (e < total) {
      s_l = (e < deg) ? csr_src[start + e] : d;
      const float4 s0 = *(const float4*)(al_s + (size_t)s_l * 8);
      const float4 s1 = *(const float4*)(al_s + (size_t)s_l * 8 + 4);
      float vv[8];
      vv[0] = s0.x + ad0.x; vv[1] = s0.y + ad0.y;
      vv[2] = s0.z + ad0.z; vv[3] = s0.w + ad0.w;
      vv[4] = s1.x + ad1.x; vv[5] = s1.y + ad1.y;
      vv[6] = s1.z + ad1.z; vv[7] = s1.w + ad1.w;
#pragma unroll
      for (int k = 0; k < 8; ++k) {
        float v = fmaxf(vv[k], NEG_SLOPE * vv[k]);
        u8[k] = __expf(v);
        den8[k] += u8[k];
      }
    }
    ssm[l] = s_l;
    ((float4*)(usm + l * 8))[0] = make_float4(u8[0], u8[1], u8[2], u8[3]);
    ((float4*)(usm + l * 8))[1] = make_float4(u8[4], u8[5], u8[6], u8[7]);

    const int ne = min(64, total - e0);
    int j = 0;
    for (; j + 8 <= ne; j += 8) {
      const int4 sa = *(const int4*)(ssm + j);
      const int4 sb = *(const int4*)(ssm + j + 4);
      const int sv[8] = {sa.x, sa.y, sa.z, sa.w, sb.x, sb.y, sb.z, sb.w};
      uint32_t wx[8];
#pragma unroll
      for (int t = 0; t < 8; ++t)
        wx[t] = *(const uint32_t*)(xcol + (size_t)sv[t] * 128);
#pragma unroll
      for (int t = 0; t < 8; ++t) {
        const float4 ua = *((const float4*)(usm + (j + t) * 8));
        const float4 ub = *((const float4*)(usm + (j + t) * 8) + 1);
        const float xlo = lo16(wx[t]);
        const float xhi = hi16(wx[t]);
        acc0[0] = fmaf(ua.x, xlo, acc0[0]); acc1[0] = fmaf(ua.x, xhi, acc1[0]);
        acc0[1] = fmaf(ua.y, xlo, acc0[1]); acc1[1] = fmaf(ua.y, xhi, acc1[1]);
        acc0[2] = fmaf(ua.z, xlo, acc0[2]); acc1[2] = fmaf(ua.z, xhi, acc1[2]);
        acc0[3] = fmaf(ua.w, xlo, acc0[3]); acc1[3] = fmaf(ua.w, xhi, acc1[3]);
        acc0[4] = fmaf(ub.x, xlo, acc0[4]); acc1[4] = fmaf(ub.x, xhi, acc1[4]);
        acc0[5] = fmaf(ub.y, xlo, acc0[5]); acc1[5] = fmaf(ub.y, xhi, acc1[5]);
        acc0[6] = fmaf(ub.z, xlo, acc0[6]); acc1[6] = fmaf(ub.z, xhi, acc1[6]);
        acc0[7] = fmaf(ub.w, xlo, acc0[7]); acc1[7] = fmaf(ub.w, xhi, acc1[7]);
      }
    }
    for (; j < ne; ++j) {
      const int s = ssm[j];
      const float4 ua = *((const float4*)(usm + j * 8));
      const float4 ub = *((const float4*)(usm + j * 8) + 1);
      const uint32_t wx = *(const uint32_t*)(xcol + (size_t)s * 128);
      const float xlo = lo16(wx);
      const float xhi = hi16(wx);
      acc0[0] = fmaf(ua.x, xlo, acc0[0]); acc1[0] = fmaf(ua.x, xhi, acc1[0]);
      acc0[1] = fmaf(ua.y, xlo, acc0[1]); acc1[1] = fmaf(ua.y, xhi, acc1[1]);
      acc0[2] = fmaf(ua.z, xlo, acc0[2]); acc1[2] = fmaf(ua.z, xhi, acc1[2]);
      acc0[3] = fmaf(ua.w, xlo, acc0[3]); acc1[3] = fmaf(ua.w, xhi, acc1[3]);
      acc0[4] = fmaf(ub.x, xlo, acc0[4]); acc1[4] = fmaf(ub.x, xhi, acc1[4]);
      acc0[5] = fmaf(ub.y, xlo, acc0[5]); acc1[5] = fmaf(ub.y, xhi, acc1[5]);
      acc0[6] = fmaf(ub.z, xlo, acc0[6]); acc1[6] = fmaf(ub.z, xhi, acc1[6]);
      acc0[7] = fmaf(ub.w, xlo, acc0[7]); acc1[7] = fmaf(ub.w, xhi, acc1[7]);
    }
  }
  // den: each lane held distinct edges (padded u=0) -> full 64-lane reduce
#pragma unroll
  for (int k = 0; k < 8; ++k) {
#pragma unroll
    for (int off = 1; off < 64; off <<= 1) den8[k] += __shfl_xor(den8[k], off);
  }
  // write agg head-major: for head h, 64 lanes write 256 B contiguous
#pragma unroll
  for (int h = 0; h < 8; ++h) {
    const float inv = 1.f / den8[h];
    const uint32_t st = (uint32_t)f2bf(acc0[h] * inv) |
                        ((uint32_t)f2bf(acc1[h] * inv) << 16);
    *(uint32_t*)(agg + ((size_t)h * Nn + d) * 128 + l * 2) = st;
  }
}

// ---------------------------------------------------------------------------
// Attention H=1, C=64 (layers 2 and 3): one wave per dst node.
// ---------------------------------------------------------------------------
__global__ __launch_bounds__(256) void attn_h1_kernel(
    const int* __restrict__ indptr, const int* __restrict__ csr_src,
    const float* __restrict__ al_s, const float* __restrict__ al_d,
    const ushort* __restrict__ hin, const float* __restrict__ bias,
    ushort* __restrict__ outp, int Nn) {
  const int w = (blockIdx.x * 256 + threadIdx.x) >> 6;
  const int l = threadIdx.x & 63;
  if (w >= Nn) return;
  const int d = w;
  const int start = indptr[d];
  const int deg = indptr[d + 1] - start;
  const int total = deg + 1;
  const int t = l >> 3;  // edge slot within chunk
  const int c8 = l & 7;  // channel block (8 ch)
  const float ald = al_d[d];
  const ushort* hl = hin + c8 * 8;

  float acc[8] = {0.f, 0.f, 0.f, 0.f, 0.f, 0.f, 0.f, 0.f};
  float den = 0.f;

  for (int e0 = 0; e0 < total; e0 += 64) {
    // stage A: all 64 lanes compute s,u for this 64-edge block
    const int e = e0 + l;
    int s_l = d;
    float u_l = 0.f;
    if (e < total) {
      s_l = (e < deg) ? csr_src[start + e] : d;
      float v = al_s[s_l] + ald;
      v = fmaxf(v, NEG_SLOPE * v);
      u_l = __expf(v);
      den += u_l;
    }
    const int ne = min(64, total - e0);
    // 2-deep pipelined chunk loop (8 edges per chunk)
    int su0 = __shfl(s_l, t);
    float uv0 = __shfl(u_l, t);
    uint4 h0 = *(const uint4*)(hl + (size_t)su0 * 64);
    int j = 0;
    for (; j + 8 < ne; j += 8) {
      const int su1 = __shfl(s_l, j + 8 + t);
      const float uv1 = __shfl(u_l, j + 8 + t);
      const uint4 h1v = *(const uint4*)(hl + (size_t)su1 * 64);
      acc[0] = fmaf(uv0, lo16(h0.x), acc[0]);
      acc[1] = fmaf(uv0, hi16(h0.x), acc[1]);
      acc[2] = fmaf(uv0, lo16(h0.y), acc[2]);
      acc[3] = fmaf(uv0, hi16(h0.y), acc[3]);
      acc[4] = fmaf(uv0, lo16(h0.z), acc[4]);
      acc[5] = fmaf(uv0, hi16(h0.z), acc[5]);
      acc[6] = fmaf(uv0, lo16(h0.w), acc[6]);
      acc[7] = fmaf(uv0, hi16(h0.w), acc[7]);
      uv0 = uv1;
      h0 = h1v;
    }
    acc[0] = fmaf(uv0, lo16(h0.x), acc[0]);
    acc[1] = fmaf(uv0, hi16(h0.x), acc[1]);
    acc[2] = fmaf(uv0, lo16(h0.y), acc[2]);
    acc[3] = fmaf(uv0, hi16(h0.y), acc[3]);
    acc[4] = fmaf(uv0, lo16(h0.z), acc[4]);
    acc[5] = fmaf(uv0, hi16(h0.z), acc[5]);
    acc[6] = fmaf(uv0, lo16(h0.w), acc[6]);
    acc[7] = fmaf(uv0, hi16(h0.w), acc[7]);
  }
  // reduce acc across the 8 edge slots (bits 3..5); c8 preserved
#pragma unroll
  for (int k = 0; k < 8; ++k) {
    acc[k] += __shfl_xor(acc[k], 8);
    acc[k] += __shfl_xor(acc[k], 16);
    acc[k] += __shfl_xor(acc[k], 32);
  }
  // den: each lane held distinct edges -> full 64-lane reduce
#pragma unroll
  for (int off = 32; off; off >>= 1) den += __shfl_xor(den, off);
  const float inv = 1.f / den;
  if (l < 8) {  // lanes 0..7: t==0, c8==l
    float o[8];
#pragma unroll
    for (int k = 0; k < 8; ++k) {
      float v = acc[k] * inv + bias[l * 8 + k];
      o[k] = (v > 0.f) ? v : __expf(v) - 1.f;
    }
    uint4 st;
    st.x = (uint32_t)f2bf(o[0]) | ((uint32_t)f2bf(o[1]) << 16);
    st.y = (uint32_t)f2bf(o[2]) | ((uint32_t)f2bf(o[3]) << 16);
    st.z = (uint32_t)f2bf(o[4]) | ((uint32_t)f2bf(o[5]) << 16);
    st.w = (uint32_t)f2bf(o[6]) | ((uint32_t)f2bf(o[7]) << 16);
    *(uint4*)(outp + (size_t)d * 64 + l * 8) = st;
  }
}

// ---------------------------------------------------------------------------
// Pool + FC: one block per graph. Segment-mean over out3 (bf16 N x 64),
// then pooled @ fcW + fcb. No global atomics.
// ---------------------------------------------------------------------------
__global__ __launch_bounds__(256) void pool_fc_kernel(
    const ushort* __restrict__ out3, const int* __restrict__ batch, int Nn,
    const float* __restrict__ fcW, const float* __restrict__ fcb,
    float* __restrict__ out) {
  __shared__ int bnds[2];
  __shared__ float sm[4 * 64];
  __shared__ float pm[64];
  const int tid = threadIdx.x;
  const int g = blockIdx.x;
  if (tid < 2) {
    int target = g + tid;
    int lo = 0, hi = Nn;
    while (lo < hi) {
      int mid = (lo + hi) >> 1;
      if (batch[mid] < target) lo = mid + 1; else hi = mid;
    }
    bnds[tid] = lo;
  }
  __syncthreads();
  const int lb = bnds[0], ub = bnds[1];

  const int ro = tid >> 3, c8 = tid & 7;
  float acc[8] = {0.f, 0.f, 0.f, 0.f, 0.f, 0.f, 0.f, 0.f};
  for (int r = lb + ro; r < ub; r += 32) {
    const uint4 hh4 = *(const uint4*)(out3 + (size_t)r * 64 + c8 * 8);
    acc[0] += lo16(hh4.x);
    acc[1] += hi16(hh4.x);
    acc[2] += lo16(hh4.y);
    acc[3] += hi16(hh4.y);
    acc[4] += lo16(hh4.z);
    acc[5] += hi16(hh4.z);
    acc[6] += lo16(hh4.w);
    acc[7] += hi16(hh4.w);
  }
#pragma unroll
  for (int k = 0; k < 8; ++k) {
    acc[k] += __shfl_xor(acc[k], 8);
    acc[k] += __shfl_xor(acc[k], 16);
    acc[k] += __shfl_xor(acc[k], 32);
  }
  const int wv = tid >> 6, ll = tid & 63;
  if (ll < 8) {
#pragma unroll
    for (int k = 0; k < 8; ++k) sm[wv * 64 + ll * 8 + k] = acc[k];
  }
  __syncthreads();
  if (tid < 64) {
    float tot = sm[tid] + sm[64 + tid] + sm[128 + tid] + sm[192 + tid];
    pm[tid] = tot / fmaxf((float)(ub - lb), 1.f);
  }
  __syncthreads();
  if (tid < 10) {
    float a = fcb[tid];
    for (int c = 0; c < 64; ++c) a = fmaf(pm[c], fcW[c * 10 + tid], a);
    out[g * 10 + tid] = a;
  }
}

// ---------------------------------------------------------------------------
extern "C" void kernel_launch(void* const* d_in, const int* in_sizes, int n_in,
                              void* d_out, int out_size, void* d_ws,
                              size_t ws_size, hipStream_t stream) {
  const float* x = (const float*)d_in[0];
  const int* ei = (const int*)d_in[1];
  const int* batch = (const int*)d_in[2];
  const float* W1 = (const float*)d_in[3];
  const float* a1s = (const float*)d_in[4];
  const float* a1d = (const float*)d_in[5];
  const float* b1 = (const float*)d_in[6];
  const float* W2 = (const float*)d_in[7];
  const float* a2s = (const float*)d_in[8];
  const float* a2d = (const float*)d_in[9];
  const float* b2 = (const float*)d_in[10];
  const float* W3 = (const float*)d_in[11];
  const float* a3s = (const float*)d_in[12];
  const float* a3d = (const float*)d_in[13];
  const float* b3 = (const float*)d_in[14];
  const float* fcW = (const float*)d_in[15];
  const float* fcb = (const float*)d_in[16];
  float* out = (float*)d_out;

  const int N = in_sizes[0] / 128;  // 50000
  const int E = in_sizes[1] / 2;    // 800000
  const int* srcp = ei;
  const int* dstp = ei + E;

  // --- workspace layout ---
  char* ws = (char*)d_ws;
  size_t off = 0;
  auto alloc = [&](size_t bytes) -> void* {
    off = (off + 255) & ~(size_t)255;
    void* p = ws + off;
    off += bytes;
    return p;
  };
  ushort* x_bf = (ushort*)alloc((size_t)N * 128 * 2);
  ushort* W1T = (ushort*)alloc(512 * 128 * 2);
  ushort* W2T = (ushort*)alloc(64 * 512 * 2);
  ushort* W3T = (ushort*)alloc(64 * 64 * 2);
  float* at_s = (float*)alloc(128 * 8 * 4);
  float* at_d = (float*)alloc(128 * 8 * 4);
  ushort* agg = (ushort*)alloc((size_t)N * 1024 * 2);   // head-major [8][N][128]
  ushort* hreg = (ushort*)alloc((size_t)4 * N * 64 * 2);  // h2/out2/h3/out3
  float* al_s1 = (float*)alloc((size_t)N * 8 * 4);
  float* al_d1 = (float*)alloc((size_t)N * 8 * 4);
  float* al_s2 = (float*)alloc((size_t)N * 4);
  float* al_d2 = (float*)alloc((size_t)N * 4);
  float* al_s3 = (float*)alloc((size_t)N * 4);
  float* al_d3 = (float*)alloc((size_t)N * 4);
  int* cnt = (int*)alloc((size_t)N * 4);
  int* fill = (int*)alloc((size_t)(N + 1) * 4);
  int* indptr = (int*)alloc((size_t)(N + 1) * 4);
  int* csr = (int*)alloc((size_t)E * 4);
  int* incbuf = (int*)alloc((size_t)N * 4);
  int* bsum = (int*)alloc(1024 * 4);

  ushort* h2 = hreg;
  ushort* out2 = hreg + (size_t)N * 64;
  ushort* h3 = hreg + (size_t)2 * N * 64;
  ushort* out3 = hreg + (size_t)3 * N * 64;

  hipMemsetAsync(cnt, 0, (size_t)N * 4, stream);

  const int scan_blocks = (N + 255) / 256;  // 196 (<256 required)
  const int row_blocks = (N / 16 + 3) / 4;
  const int tile_blocks = (N + 15) / 16;  // 3125

  // prep: x cast + weight transposes + CSR count + at (W1^T a) fold
  const int n_x4 = N * 128 / 4;
  const int prep_total = n_x4 + 512 * 128 + 64 * 512 + 64 * 64 + E + 2048;
  prep_kernel<<<(prep_total + 255) / 256, 256, 0, stream>>>(
      (const float4*)x, (uint2*)x_bf, n_x4, W1, W1T, W2, W2T, W3, W3T, dstp,
      cnt, a1s, a1d, at_s, at_d, E);

  // layer-1 al from x directly
  algemm_kernel<<<(N + 255) / 256, 256, 0, stream>>>(x_bf, at_s, at_d, al_s1,
                                                     al_d1, N);
  // CSR build
  scan_block<<<scan_blocks, 256, 0, stream>>>(cnt, incbuf, bsum, N);
  scan_final2<<<scan_blocks, 256, 0, stream>>>(incbuf, bsum, indptr, fill, N);
  scatter_kernel<<<(E + 255) / 256, 256, 0, stream>>>(srcp, dstp, fill, csr, E);

  // Layer 1: attention in x-space (256 B rows), head-major agg
  attn1x_kernel<<<(N + 3) / 4, 256, 0, stream>>>(indptr, csr, al_s1, al_d1,
                                                 x_bf, agg, N);
  // Fused: out1 = ELU(agg@W1+b1) kept in LDS -> h2 = out1@W2 (+al2)
  gemm12_kernel<<<tile_blocks, 256, 0, stream>>>(agg, W1T, b1, W2T, a2s, a2d,
                                                 h2, al_s2, al_d2, N);
  attn_h1_kernel<<<(N + 3) / 4, 256, 0, stream>>>(indptr, csr, al_s2, al_d2, h2,
                                                  b2, out2, N);

  // Layer 3
  gemm_n64_al<<<dim3(1, row_blocks), 256, 0, stream>>>(out2, W3T, h3, a3s, a3d,
                                                       al_s3, al_d3, N, 64);
  attn_h1_kernel<<<(N + 3) / 4, 256, 0, stream>>>(indptr, csr, al_s3, al_d3, h3,
                                                  b3, out3, N);

  // Pool + FC (no atomics)
  pool_fc_kernel<<<64, 256, 0, stream>>>(out3, batch, N, fcW, fcb, out);
}

// Round 7
// 413.102 us; speedup vs baseline: 1.0916x; 1.0916x over previous
//
#include <hip/hip_runtime.h>
#include <hip/hip_bf16.h>
#include <cstdint>

#define NEG_SLOPE 0.2f

typedef __attribute__((ext_vector_type(8))) short bf16x8;
typedef __attribute__((ext_vector_type(4))) float f32x4;

__device__ __forceinline__ float bf2f(uint32_t u) {
  union { float f; uint32_t i; } v;
  v.i = u << 16;
  return v.f;
}
__device__ __forceinline__ float lo16(uint32_t u) {
  union { float f; uint32_t i; } v;
  v.i = u << 16;
  return v.f;
}
__device__ __forceinline__ float hi16(uint32_t u) {
  union { float f; uint32_t i; } v;
  v.i = u & 0xffff0000u;
  return v.f;
}
__device__ __forceinline__ ushort f2bf(float f) {
  union { float f; uint32_t i; } v;
  v.f = f;
  uint32_t r = v.i + 0x7FFF + ((v.i >> 16) & 1);  // round-nearest-even
  return (ushort)(r >> 16);
}

// ---------------------------------------------------------------------------
// prep: cast x -> bf16, transpose+cast W1/W2/W3, CSR count pass,
// and fold attention vectors through W1:  at_s[k][h] = sum_c W1[k][h*64+c]*a1s[h][c]
// ---------------------------------------------------------------------------
__global__ void prep_kernel(const float4* __restrict__ x,
                            uint2* __restrict__ x_bf, int n_x4,
                            const float* __restrict__ W1,
                            ushort* __restrict__ W1T,
                            const float* __restrict__ W2,
                            ushort* __restrict__ W2T,
                            const float* __restrict__ W3,
                            ushort* __restrict__ W3T,
                            const int* __restrict__ dst, int* __restrict__ cnt,
                            const float* __restrict__ a1s,
                            const float* __restrict__ a1d,
                            float* __restrict__ at_s, float* __restrict__ at_d,
                            int E) {
  int i = blockIdx.x * 256 + threadIdx.x;
  const int r0 = n_x4;
  const int r1 = r0 + 512 * 128;
  const int r2 = r1 + 64 * 512;
  const int r3 = r2 + 64 * 64;
  const int r4 = r3 + E;
  const int r5 = r4 + 1024;
  const int r6 = r5 + 1024;
  if (i < r0) {
    float4 v = x[i];
    uint2 o;
    o.x = (uint32_t)f2bf(v.x) | ((uint32_t)f2bf(v.y) << 16);
    o.y = (uint32_t)f2bf(v.z) | ((uint32_t)f2bf(v.w) << 16);
    x_bf[i] = o;
  } else if (i < r1) {
    int idx = i - r0;
    int n = idx >> 7, k = idx & 127;
    W1T[idx] = f2bf(W1[(size_t)k * 512 + n]);
  } else if (i < r2) {
    int idx = i - r1;
    int n = idx >> 9, k = idx & 511;
    W2T[idx] = f2bf(W2[(size_t)k * 64 + n]);
  } else if (i < r3) {
    int idx = i - r2;
    int n = idx >> 6, k = idx & 63;
    W3T[idx] = f2bf(W3[(size_t)k * 64 + n]);
  } else if (i < r4) {
    atomicAdd(&cnt[dst[i - r3]], 1);
  } else if (i < r5) {
    int idx = i - r4;  // k*8 + h
    int k = idx >> 3, h = idx & 7;
    float a = 0.f;
    for (int c = 0; c < 64; ++c)
      a = fmaf(W1[(size_t)k * 512 + h * 64 + c], a1s[h * 64 + c], a);
    at_s[idx] = a;
  } else if (i < r6) {
    int idx = i - r5;
    int k = idx >> 3, h = idx & 7;
    float a = 0.f;
    for (int c = 0; c < 64; ++c)
      a = fmaf(W1[(size_t)k * 512 + h * 64 + c], a1d[h * 64 + c], a);
    at_d[idx] = a;
  }
}

// ---------------------------------------------------------------------------
// Layer-1 al from x directly: al_s[n][h] = x[n] . at_s[:,h]  (K=128, 16 outs)
// ---------------------------------------------------------------------------
__global__ __launch_bounds__(256) void algemm_kernel(
    const ushort* __restrict__ x_bf, const float* __restrict__ at_s,
    const float* __restrict__ at_d, float* __restrict__ al_s,
    float* __restrict__ al_d, int Nn) {
  const int n = blockIdx.x * 256 + threadIdx.x;
  if (n >= Nn) return;
  float as8[8] = {}, ad8[8] = {};
  const ushort* xp = x_bf + (size_t)n * 128;
  for (int k0 = 0; k0 < 128; k0 += 8) {
    const uint4 xw = *(const uint4*)(xp + k0);
    const uint32_t ww0 = xw.x, ww1 = xw.y, ww2 = xw.z, ww3 = xw.w;
    float xv[8];
    xv[0] = lo16(ww0); xv[1] = hi16(ww0);
    xv[2] = lo16(ww1); xv[3] = hi16(ww1);
    xv[4] = lo16(ww2); xv[5] = hi16(ww2);
    xv[6] = lo16(ww3); xv[7] = hi16(ww3);
#pragma unroll
    for (int t = 0; t < 8; ++t) {
      const int k = k0 + t;
#pragma unroll
      for (int h = 0; h < 8; ++h) {
        as8[h] = fmaf(xv[t], at_s[k * 8 + h], as8[h]);
        ad8[h] = fmaf(xv[t], at_d[k * 8 + h], ad8[h]);
      }
    }
  }
  float4* ps = (float4*)(al_s + (size_t)n * 8);
  ps[0] = make_float4(as8[0], as8[1], as8[2], as8[3]);
  ps[1] = make_float4(as8[4], as8[5], as8[6], as8[7]);
  float4* pd = (float4*)(al_d + (size_t)n * 8);
  pd[0] = make_float4(ad8[0], ad8[1], ad8[2], ad8[3]);
  pd[1] = make_float4(ad8[4], ad8[5], ad8[6], ad8[7]);
}

// ---------------------------------------------------------------------------
// GEMM (N=64) + fused al (H=1): C[M,64] = A[M,K] @ BT[64,K].  (layer 3)
// ---------------------------------------------------------------------------
__global__ __launch_bounds__(256) void gemm_n64_al(
    const ushort* __restrict__ A, const ushort* __restrict__ BT,
    ushort* __restrict__ C, const float* __restrict__ asrc,
    const float* __restrict__ adst, float* __restrict__ al_s,
    float* __restrict__ al_d, int M, int K) {
  const int wave = threadIdx.x >> 6;
  const int lane = threadIdx.x & 63;
  const int rt = blockIdx.y * 4 + wave;
  const int r0 = rt * 16;
  if (r0 >= M) return;
  const int l15 = lane & 15, q = lane >> 4;
  const ushort* Ap = A + (size_t)(r0 + l15) * K + q * 8;
  f32x4 acc[4] = {};
  for (int k0 = 0; k0 < K; k0 += 32) {
    bf16x8 a = *(const bf16x8*)(Ap + k0);
#pragma unroll
    for (int j = 0; j < 4; ++j) {
      const bf16x8 b =
          *(const bf16x8*)(BT + (size_t)(j * 16 + l15) * K + q * 8 + k0);
      acc[j] = __builtin_amdgcn_mfma_f32_16x16x32_bf16(a, b, acc[j], 0, 0, 0);
    }
  }
#pragma unroll
  for (int j = 0; j < 4; ++j)
#pragma unroll
    for (int r = 0; r < 4; ++r) {
      int row = r0 + q * 4 + r;
      C[(size_t)row * 64 + j * 16 + l15] = f2bf(acc[j][r]);
    }
  float als_p[4] = {0.f, 0.f, 0.f, 0.f};
  float ald_p[4] = {0.f, 0.f, 0.f, 0.f};
#pragma unroll
  for (int j = 0; j < 4; ++j) {
    float wsc = asrc[j * 16 + l15];
    float wdc = adst[j * 16 + l15];
#pragma unroll
    for (int r = 0; r < 4; ++r) {
      als_p[r] = fmaf(acc[j][r], wsc, als_p[r]);
      ald_p[r] = fmaf(acc[j][r], wdc, ald_p[r]);
    }
  }
#pragma unroll
  for (int r = 0; r < 4; ++r) {
    float vs = als_p[r], vd = ald_p[r];
#pragma unroll
    for (int off = 1; off < 16; off <<= 1) {
      vs += __shfl_xor(vs, off);
      vd += __shfl_xor(vd, off);
    }
    if (l15 == 0) {
      int row = r0 + q * 4 + r;
      al_s[row] = vs;
      al_d[row] = vd;
    }
  }
}

// ---------------------------------------------------------------------------
// FUSED layers 1b+2a, 64-row tile, register-blocked.
//  stage 1: o1t[64][512] = ELU(agg_tile @ W1 (per-head) + b1) -> LDS.
//    Per wave, per head: W1T fragments hoisted once per k-step; 4 row-subtile
//    A fragments; 16 INDEPENDENT MFMA chains (acc[4][4]) -> real ILP/MLP and
//    ~130 VGPRs (defeats the 28-VGPR serial load-use chains of the 16-row ver).
//  stage 2: h2[64][64] = o1t @ W2T (K=512), 4 independent acc chains, + al2.
// ---------------------------------------------------------------------------
__global__ __launch_bounds__(256) void gemm12_kernel(
    const ushort* __restrict__ agg, const ushort* __restrict__ W1T,
    const float* __restrict__ b1, const ushort* __restrict__ W2T,
    const float* __restrict__ a2s, const float* __restrict__ a2d,
    ushort* __restrict__ h2, float* __restrict__ al_s,
    float* __restrict__ al_d, int M) {
  __shared__ ushort o1t[64][520];  // padded stride (1040 B): 2-way banks only
  __shared__ float als_sm[4][64];
  __shared__ float ald_sm[4][64];
  const int w = threadIdx.x >> 6;
  const int lane = threadIdx.x & 63;
  const int l15 = lane & 15, q = lane >> 4;
  const int r0 = blockIdx.x * 64;

  int rrd[4];
#pragma unroll
  for (int rt = 0; rt < 4; ++rt) rrd[rt] = min(r0 + rt * 16 + l15, M - 1);

  // ---- stage 1: two heads per wave, one at a time
#pragma unroll
  for (int hi = 0; hi < 2; ++hi) {
    const int hd = w * 2 + hi;
    f32x4 acc[4][4] = {};
    for (int k0 = 0; k0 < 128; k0 += 32) {
      bf16x8 wf[4];
#pragma unroll
      for (int j = 0; j < 4; ++j)
        wf[j] = *(const bf16x8*)(W1T +
                                 (size_t)(hd * 64 + j * 16 + l15) * 128 +
                                 q * 8 + k0);
      bf16x8 af[4];
#pragma unroll
      for (int rt = 0; rt < 4; ++rt)
        af[rt] = *(const bf16x8*)(agg + ((size_t)hd * M + rrd[rt]) * 128 +
                                  q * 8 + k0);
#pragma unroll
      for (int rt = 0; rt < 4; ++rt)
#pragma unroll
        for (int j = 0; j < 4; ++j)
          acc[rt][j] = __builtin_amdgcn_mfma_f32_16x16x32_bf16(
              af[rt], wf[j], acc[rt][j], 0, 0, 0);
    }
#pragma unroll
    for (int j = 0; j < 4; ++j) {
      const int col = hd * 64 + j * 16 + l15;
      const float bb = b1[col];
#pragma unroll
      for (int rt = 0; rt < 4; ++rt)
#pragma unroll
        for (int r = 0; r < 4; ++r) {
          float v = acc[rt][j][r] + bb;
          v = (v > 0.f) ? v : __expf(v) - 1.f;
          o1t[rt * 16 + q * 4 + r][col] = f2bf(v);
        }
    }
  }
  __syncthreads();

  // ---- stage 2: wave w computes h2 cols w*16..w*16+15, K=512 from LDS
  f32x4 acc2[4] = {};
  for (int k0 = 0; k0 < 512; k0 += 32) {
    const bf16x8 b = *(const bf16x8*)(W2T +
                                      (size_t)(w * 16 + l15) * 512 + q * 8 +
                                      k0);
#pragma unroll
    for (int rt = 0; rt < 4; ++rt) {
      const bf16x8 a = *(const bf16x8*)(&o1t[rt * 16 + l15][k0 + q * 8]);
      acc2[rt] = __builtin_amdgcn_mfma_f32_16x16x32_bf16(a, b, acc2[rt], 0, 0, 0);
    }
  }
  const float wsc = a2s[w * 16 + l15];
  const float wdc = a2d[w * 16 + l15];
#pragma unroll
  for (int rt = 0; rt < 4; ++rt)
#pragma unroll
    for (int r = 0; r < 4; ++r) {
      const int row = r0 + rt * 16 + q * 4 + r;
      if (row < M) h2[(size_t)row * 64 + w * 16 + l15] = f2bf(acc2[rt][r]);
      float vs = acc2[rt][r] * wsc, vd = acc2[rt][r] * wdc;
#pragma unroll
      for (int off = 1; off < 16; off <<= 1) {
        vs += __shfl_xor(vs, off);
        vd += __shfl_xor(vd, off);
      }
      if (l15 == 0) {
        als_sm[w][rt * 16 + q * 4 + r] = vs;
        ald_sm[w][rt * 16 + q * 4 + r] = vd;
      }
    }
  __syncthreads();
  if (threadIdx.x < 64) {
    const int row = r0 + threadIdx.x;
    if (row < M) {
      const int t = threadIdx.x;
      al_s[row] = als_sm[0][t] + als_sm[1][t] + als_sm[2][t] + als_sm[3][t];
      al_d[row] = ald_sm[0][t] + ald_sm[1][t] + ald_sm[2][t] + ald_sm[3][t];
    }
  }
}

// ---------------------------------------------------------------------------
// CSR: per-block inclusive scan (block sums to bsum)
// ---------------------------------------------------------------------------
__global__ void scan_block(const int* __restrict__ in, int* __restrict__ out,
                           int* __restrict__ bsum, int n) {
  __shared__ int sm[256];
  int gid = blockIdx.x * 256 + threadIdx.x;
  int v = (gid < n) ? in[gid] : 0;
  sm[threadIdx.x] = v;
  __syncthreads();
  for (int off = 1; off < 256; off <<= 1) {
    int t = (threadIdx.x >= off) ? sm[threadIdx.x - off] : 0;
    __syncthreads();
    sm[threadIdx.x] += t;
    __syncthreads();
  }
  if (gid < n) out[gid] = sm[threadIdx.x];
  if (threadIdx.x == 255) bsum[blockIdx.x] = sm[255];
}

__global__ void scan_final2(const int* __restrict__ inc,
                            const int* __restrict__ bsum,
                            int* __restrict__ indptr, int* __restrict__ fill,
                            int n) {
  __shared__ int sm[256];
  const int t = threadIdx.x, bx = blockIdx.x;
  sm[t] = (t < bx) ? bsum[t] : 0;  // gridDim <= 256
  __syncthreads();
  for (int off = 128; off; off >>= 1) {
    if (t < off) sm[t] += sm[t + off];
    __syncthreads();
  }
  const int prefix = sm[0];
  int gid = bx * 256 + t;
  if (gid < n) {
    int val = inc[gid] + prefix;
    indptr[gid + 1] = val;
    fill[gid + 1] = val;
  }
  if (gid == 0) {
    indptr[0] = 0;
    fill[0] = 0;
  }
}

__global__ void scatter_kernel(const int* __restrict__ src,
                               const int* __restrict__ dst,
                               int* __restrict__ fill,
                               int* __restrict__ csr_src, int E) {
  int e = blockIdx.x * 256 + threadIdx.x;
  if (e < E) {
    int pos = atomicAdd(&fill[dst[e]], 1);
    csr_src[pos] = src[e];
  }
}

// ---------------------------------------------------------------------------
// Layer-1 attention in x-space, cooperative-row layout + 8-edge batched loads.
// Output agg is HEAD-MAJOR [8][N][128].
// ---------------------------------------------------------------------------
__global__ __launch_bounds__(256) void attn1x_kernel(
    const int* __restrict__ indptr, const int* __restrict__ csr_src,
    const float* __restrict__ al_s, const float* __restrict__ al_d,
    const ushort* __restrict__ x_bf, ushort* __restrict__ agg, int Nn) {
  __shared__ float u_sm[4][64 * 8];
  __shared__ int s_sm[4][64];
  const int wv = threadIdx.x >> 6;
  const int l = threadIdx.x & 63;
  const int w = (blockIdx.x * 256 + threadIdx.x) >> 6;
  if (w >= Nn) return;
  const int d = w;
  const int start = indptr[d];
  const int deg = indptr[d + 1] - start;
  const int total = deg + 1;  // + self loop
  const float4 ad0 = *(const float4*)(al_d + (size_t)d * 8);
  const float4 ad1 = *(const float4*)(al_d + (size_t)d * 8 + 4);
  const ushort* xcol = x_bf + l * 2;  // channel pair (2l, 2l+1)

  float acc0[8] = {};  // per-head accum, ch 2l
  float acc1[8] = {};  // per-head accum, ch 2l+1
  float den8[8] = {};
  float* usm = u_sm[wv];
  int* ssm = s_sm[wv];

  for (int e0 = 0; e0 < total; e0 += 64) {
    // ---- stage A: lane-parallel (s, u[8]) for this 64-edge block
    const int e = e0 + l;
    int s_l = d;
    float u8[8] = {};
    if (e < total) {
      s_l = (e < deg) ? csr_src[start + e] : d;
      const float4 s0 = *(const float4*)(al_s + (size_t)s_l * 8);
      const float4 s1 = *(const float4*)(al_s + (size_t)s_l * 8 + 4);
      float vv[8];
      vv[0] = s0.x + ad0.x; vv[1] = s0.y + ad0.y;
      vv[2] = s0.z + ad0.z; vv[3] = s0.w + ad0.w;
      vv[4] = s1.x + ad1.x; vv[5] = s1.y + ad1.y;
      vv[6] = s1.z + ad1.z; vv[7] = s1.w + ad1.w;
#pragma unroll
      for (int k = 0; k < 8; ++k) {
        float v = fmaxf(vv[k], NEG_SLOPE * vv[k]);
        u8[k] = __expf(v);
        den8[k] += u8[k];
      }
    }
    ssm[l] = s_l;
    ((float4*)(usm + l * 8))[0] = make_float4(u8[0], u8[1], u8[2], u8[3]);
    ((float4*)(usm + l * 8))[1] = make_float4(u8[4], u8[5], u8[6], u8[7]);

    const int ne = min(64, total - e0);
    int j = 0;
    for (; j + 8 <= ne; j += 8) {
      const int4 sa = *(const int4*)(ssm + j);
      const int4 sb = *(const int4*)(ssm + j + 4);
      const int sv[8] = {sa.x, sa.y, sa.z, sa.w, sb.x, sb.y, sb.z, sb.w};
      uint32_t wx[8];
#pragma unroll
      for (int t = 0; t < 8; ++t)
        wx[t] = *(const uint32_t*)(xcol + (size_t)sv[t] * 128);
#pragma unroll
      for (int t = 0; t < 8; ++t) {
        const float4 ua = *((const float4*)(usm + (j + t) * 8));
        const float4 ub = *((const float4*)(usm + (j + t) * 8) + 1);
        const float xlo = lo16(wx[t]);
        const float xhi = hi16(wx[t]);
        acc0[0] = fmaf(ua.x, xlo, acc0[0]); acc1[0] = fmaf(ua.x, xhi, acc1[0]);
        acc0[1] = fmaf(ua.y, xlo, acc0[1]); acc1[1] = fmaf(ua.y, xhi, acc1[1]);
        acc0[2] = fmaf(ua.z, xlo, acc0[2]); acc1[2] = fmaf(ua.z, xhi, acc1[2]);
        acc0[3] = fmaf(ua.w, xlo, acc0[3]); acc1[3] = fmaf(ua.w, xhi, acc1[3]);
        acc0[4] = fmaf(ub.x, xlo, acc0[4]); acc1[4] = fmaf(ub.x, xhi, acc1[4]);
        acc0[5] = fmaf(ub.y, xlo, acc0[5]); acc1[5] = fmaf(ub.y, xhi, acc1[5]);
        acc0[6] = fmaf(ub.z, xlo, acc0[6]); acc1[6] = fmaf(ub.z, xhi, acc1[6]);
        acc0[7] = fmaf(ub.w, xlo, acc0[7]); acc1[7] = fmaf(ub.w, xhi, acc1[7]);
      }
    }
    for (; j < ne; ++j) {
      const int s = ssm[j];
      const float4 ua = *((const float4*)(usm + j * 8));
      const float4 ub = *((const float4*)(usm + j * 8) + 1);
      const uint32_t wx = *(const uint32_t*)(xcol + (size_t)s * 128);
      const float xlo = lo16(wx);
      const float xhi = hi16(wx);
      acc0[0] = fmaf(ua.x, xlo, acc0[0]); acc1[0] = fmaf(ua.x, xhi, acc1[0]);
      acc0[1] = fmaf(ua.y, xlo, acc0[1]); acc1[1] = fmaf(ua.y, xhi, acc1[1]);
      acc0[2] = fmaf(ua.z, xlo, acc0[2]); acc1[2] = fmaf(ua.z, xhi, acc1[2]);
      acc0[3] = fmaf(ua.w, xlo, acc0[3]); acc1[3] = fmaf(ua.w, xhi, acc1[3]);
      acc0[4] = fmaf(ub.x, xlo, acc0[4]); acc1[4] = fmaf(ub.x, xhi, acc1[4]);
      acc0[5] = fmaf(ub.y, xlo, acc0[5]); acc1[5] = fmaf(ub.y, xhi, acc1[5]);
      acc0[6] = fmaf(ub.z, xlo, acc0[6]); acc1[6] = fmaf(ub.z, xhi, acc1[6]);
      acc0[7] = fmaf(ub.w, xlo, acc0[7]); acc1[7] = fmaf(ub.w, xhi, acc1[7]);
    }
  }
  // den: each lane held distinct edges (padded u=0) -> full 64-lane reduce
#pragma unroll
  for (int k = 0; k < 8; ++k) {
#pragma unroll
    for (int off = 1; off < 64; off <<= 1) den8[k] += __shfl_xor(den8[k], off);
  }
  // write agg head-major: for head h, 64 lanes write 256 B contiguous
#pragma unroll
  for (int h = 0; h < 8; ++h) {
    const float inv = 1.f / den8[h];
    const uint32_t st = (uint32_t)f2bf(acc0[h] * inv) |
                        ((uint32_t)f2bf(acc1[h] * inv) << 16);
    *(uint32_t*)(agg + ((size_t)h * Nn + d) * 128 + l * 2) = st;
  }
}

// ---------------------------------------------------------------------------
// Attention H=1, C=64 (layers 2 and 3): one wave per dst node.
// ---------------------------------------------------------------------------
__global__ __launch_bounds__(256) void attn_h1_kernel(
    const int* __restrict__ indptr, const int* __restrict__ csr_src,
    const float* __restrict__ al_s, const float* __restrict__ al_d,
    const ushort* __restrict__ hin, const float* __restrict__ bias,
    ushort* __restrict__ outp, int Nn) {
  const int w = (blockIdx.x * 256 + threadIdx.x) >> 6;
  const int l = threadIdx.x & 63;
  if (w >= Nn) return;
  const int d = w;
  const int start = indptr[d];
  const int deg = indptr[d + 1] - start;
  const int total = deg + 1;
  const int t = l >> 3;  // edge slot within chunk
  const int c8 = l & 7;  // channel block (8 ch)
  const float ald = al_d[d];
  const ushort* hl = hin + c8 * 8;

  float acc[8] = {0.f, 0.f, 0.f, 0.f, 0.f, 0.f, 0.f, 0.f};
  float den = 0.f;

  for (int e0 = 0; e0 < total; e0 += 64) {
    // stage A: all 64 lanes compute s,u for this 64-edge block
    const int e = e0 + l;
    int s_l = d;
    float u_l = 0.f;
    if (e < total) {
      s_l = (e < deg) ? csr_src[start + e] : d;
      float v = al_s[s_l] + ald;
      v = fmaxf(v, NEG_SLOPE * v);
      u_l = __expf(v);
      den += u_l;
    }
    const int ne = min(64, total - e0);
    // 2-deep pipelined chunk loop (8 edges per chunk)
    int su0 = __shfl(s_l, t);
    float uv0 = __shfl(u_l, t);
    uint4 h0 = *(const uint4*)(hl + (size_t)su0 * 64);
    int j = 0;
    for (; j + 8 < ne; j += 8) {
      const int su1 = __shfl(s_l, j + 8 + t);
      const float uv1 = __shfl(u_l, j + 8 + t);
      const uint4 h1v = *(const uint4*)(hl + (size_t)su1 * 64);
      acc[0] = fmaf(uv0, lo16(h0.x), acc[0]);
      acc[1] = fmaf(uv0, hi16(h0.x), acc[1]);
      acc[2] = fmaf(uv0, lo16(h0.y), acc[2]);
      acc[3] = fmaf(uv0, hi16(h0.y), acc[3]);
      acc[4] = fmaf(uv0, lo16(h0.z), acc[4]);
      acc[5] = fmaf(uv0, hi16(h0.z), acc[5]);
      acc[6] = fmaf(uv0, lo16(h0.w), acc[6]);
      acc[7] = fmaf(uv0, hi16(h0.w), acc[7]);
      uv0 = uv1;
      h0 = h1v;
    }
    acc[0] = fmaf(uv0, lo16(h0.x), acc[0]);
    acc[1] = fmaf(uv0, hi16(h0.x), acc[1]);
    acc[2] = fmaf(uv0, lo16(h0.y), acc[2]);
    acc[3] = fmaf(uv0, hi16(h0.y), acc[3]);
    acc[4] = fmaf(uv0, lo16(h0.z), acc[4]);
    acc[5] = fmaf(uv0, hi16(h0.z), acc[5]);
    acc[6] = fmaf(uv0, lo16(h0.w), acc[6]);
    acc[7] = fmaf(uv0, hi16(h0.w), acc[7]);
  }
  // reduce acc across the 8 edge slots (bits 3..5); c8 preserved
#pragma unroll
  for (int k = 0; k < 8; ++k) {
    acc[k] += __shfl_xor(acc[k], 8);
    acc[k] += __shfl_xor(acc[k], 16);
    acc[k] += __shfl_xor(acc[k], 32);
  }
  // den: each lane held distinct edges -> full 64-lane reduce
#pragma unroll
  for (int off = 32; off; off >>= 1) den += __shfl_xor(den, off);
  const float inv = 1.f / den;
  if (l < 8) {  // lanes 0..7: t==0, c8==l
    float o[8];
#pragma unroll
    for (int k = 0; k < 8; ++k) {
      float v = acc[k] * inv + bias[l * 8 + k];
      o[k] = (v > 0.f) ? v : __expf(v) - 1.f;
    }
    uint4 st;
    st.x = (uint32_t)f2bf(o[0]) | ((uint32_t)f2bf(o[1]) << 16);
    st.y = (uint32_t)f2bf(o[2]) | ((uint32_t)f2bf(o[3]) << 16);
    st.z = (uint32_t)f2bf(o[4]) | ((uint32_t)f2bf(o[5]) << 16);
    st.w = (uint32_t)f2bf(o[6]) | ((uint32_t)f2bf(o[7]) << 16);
    *(uint4*)(outp + (size_t)d * 64 + l * 8) = st;
  }
}

// ---------------------------------------------------------------------------
// Pool + FC: one block per graph. Segment-mean over out3 (bf16 N x 64),
// then pooled @ fcW + fcb. No global atomics.
// ---------------------------------------------------------------------------
__global__ __launch_bounds__(256) void pool_fc_kernel(
    const ushort* __restrict__ out3, const int* __restrict__ batch, int Nn,
    const float* __restrict__ fcW, const float* __restrict__ fcb,
    float* __restrict__ out) {
  __shared__ int bnds[2];
  __shared__ float sm[4 * 64];
  __shared__ float pm[64];
  const int tid = threadIdx.x;
  const int g = blockIdx.x;
  if (tid < 2) {
    int target = g + tid;
    int lo = 0, hi = Nn;
    while (lo < hi) {
      int mid = (lo + hi) >> 1;
      if (batch[mid] < target) lo = mid + 1; else hi = mid;
    }
    bnds[tid] = lo;
  }
  __syncthreads();
  const int lb = bnds[0], ub = bnds[1];

  const int ro = tid >> 3, c8 = tid & 7;
  float acc[8] = {0.f, 0.f, 0.f, 0.f, 0.f, 0.f, 0.f, 0.f};
  for (int r = lb + ro; r < ub; r += 32) {
    const uint4 hh4 = *(const uint4*)(out3 + (size_t)r * 64 + c8 * 8);
    acc[0] += lo16(hh4.x);
    acc[1] += hi16(hh4.x);
    acc[2] += lo16(hh4.y);
    acc[3] += hi16(hh4.y);
    acc[4] += lo16(hh4.z);
    acc[5] += hi16(hh4.z);
    acc[6] += lo16(hh4.w);
    acc[7] += hi16(hh4.w);
  }
#pragma unroll
  for (int k = 0; k < 8; ++k) {
    acc[k] += __shfl_xor(acc[k], 8);
    acc[k] += __shfl_xor(acc[k], 16);
    acc[k] += __shfl_xor(acc[k], 32);
  }
  const int wv = tid >> 6, ll = tid & 63;
  if (ll < 8) {
#pragma unroll
    for (int k = 0; k < 8; ++k) sm[wv * 64 + ll * 8 + k] = acc[k];
  }
  __syncthreads();
  if (tid < 64) {
    float tot = sm[tid] + sm[64 + tid] + sm[128 + tid] + sm[192 + tid];
    pm[tid] = tot / fmaxf((float)(ub - lb), 1.f);
  }
  __syncthreads();
  if (tid < 10) {
    float a = fcb[tid];
    for (int c = 0; c < 64; ++c) a = fmaf(pm[c], fcW[c * 10 + tid], a);
    out[g * 10 + tid] = a;
  }
}

// ---------------------------------------------------------------------------
extern "C" void kernel_launch(void* const* d_in, const int* in_sizes, int n_in,
                              void* d_out, int out_size, void* d_ws,
                              size_t ws_size, hipStream_t stream) {
  const float* x = (const float*)d_in[0];
  const int* ei = (const int*)d_in[1];
  const int* batch = (const int*)d_in[2];
  const float* W1 = (const float*)d_in[3];
  const float* a1s = (const float*)d_in[4];
  const float* a1d = (const float*)d_in[5];
  const float* b1 = (const float*)d_in[6];
  const float* W2 = (const float*)d_in[7];
  const float* a2s = (const float*)d_in[8];
  const float* a2d = (const float*)d_in[9];
  const float* b2 = (const float*)d_in[10];
  const float* W3 = (const float*)d_in[11];
  const float* a3s = (const float*)d_in[12];
  const float* a3d = (const float*)d_in[13];
  const float* b3 = (const float*)d_in[14];
  const float* fcW = (const float*)d_in[15];
  const float* fcb = (const float*)d_in[16];
  float* out = (float*)d_out;

  const int N = in_sizes[0] / 128;  // 50000
  const int E = in_sizes[1] / 2;    // 800000
  const int* srcp = ei;
  const int* dstp = ei + E;

  // --- workspace layout ---
  char* ws = (char*)d_ws;
  size_t off = 0;
  auto alloc = [&](size_t bytes) -> void* {
    off = (off + 255) & ~(size_t)255;
    void* p = ws + off;
    off += bytes;
    return p;
  };
  ushort* x_bf = (ushort*)alloc((size_t)N * 128 * 2);
  ushort* W1T = (ushort*)alloc(512 * 128 * 2);
  ushort* W2T = (ushort*)alloc(64 * 512 * 2);
  ushort* W3T = (ushort*)alloc(64 * 64 * 2);
  float* at_s = (float*)alloc(128 * 8 * 4);
  float* at_d = (float*)alloc(128 * 8 * 4);
  ushort* agg = (ushort*)alloc((size_t)N * 1024 * 2);   // head-major [8][N][128]
  ushort* hreg = (ushort*)alloc((size_t)4 * N * 64 * 2);  // h2/out2/h3/out3
  float* al_s1 = (float*)alloc((size_t)N * 8 * 4);
  float* al_d1 = (float*)alloc((size_t)N * 8 * 4);
  float* al_s2 = (float*)alloc((size_t)N * 4);
  float* al_d2 = (float*)alloc((size_t)N * 4);
  float* al_s3 = (float*)alloc((size_t)N * 4);
  float* al_d3 = (float*)alloc((size_t)N * 4);
  int* cnt = (int*)alloc((size_t)N * 4);
  int* fill = (int*)alloc((size_t)(N + 1) * 4);
  int* indptr = (int*)alloc((size_t)(N + 1) * 4);
  int* csr = (int*)alloc((size_t)E * 4);
  int* incbuf = (int*)alloc((size_t)N * 4);
  int* bsum = (int*)alloc(1024 * 4);

  ushort* h2 = hreg;
  ushort* out2 = hreg + (size_t)N * 64;
  ushort* h3 = hreg + (size_t)2 * N * 64;
  ushort* out3 = hreg + (size_t)3 * N * 64;

  hipMemsetAsync(cnt, 0, (size_t)N * 4, stream);

  const int scan_blocks = (N + 255) / 256;  // 196 (<256 required)
  const int row_blocks = (N / 16 + 3) / 4;
  const int tile_blocks = (N + 63) / 64;  // 782

  // prep: x cast + weight transposes + CSR count + at (W1^T a) fold
  const int n_x4 = N * 128 / 4;
  const int prep_total = n_x4 + 512 * 128 + 64 * 512 + 64 * 64 + E + 2048;
  prep_kernel<<<(prep_total + 255) / 256, 256, 0, stream>>>(
      (const float4*)x, (uint2*)x_bf, n_x4, W1, W1T, W2, W2T, W3, W3T, dstp,
      cnt, a1s, a1d, at_s, at_d, E);

  // layer-1 al from x directly
  algemm_kernel<<<(N + 255) / 256, 256, 0, stream>>>(x_bf, at_s, at_d, al_s1,
                                                     al_d1, N);
  // CSR build
  scan_block<<<scan_blocks, 256, 0, stream>>>(cnt, incbuf, bsum, N);
  scan_final2<<<scan_blocks, 256, 0, stream>>>(incbuf, bsum, indptr, fill, N);
  scatter_kernel<<<(E + 255) / 256, 256, 0, stream>>>(srcp, dstp, fill, csr, E);

  // Layer 1: attention in x-space (256 B rows), head-major agg
  attn1x_kernel<<<(N + 3) / 4, 256, 0, stream>>>(indptr, csr, al_s1, al_d1,
                                                 x_bf, agg, N);
  // Fused: out1 = ELU(agg@W1+b1) kept in LDS -> h2 = out1@W2 (+al2)
  gemm12_kernel<<<tile_blocks, 256, 0, stream>>>(agg, W1T, b1, W2T, a2s, a2d,
                                                 h2, al_s2, al_d2, N);
  attn_h1_kernel<<<(N + 3) / 4, 256, 0, stream>>>(indptr, csr, al_s2, al_d2, h2,
                                                  b2, out2, N);

  // Layer 3
  gemm_n64_al<<<dim3(1, row_blocks), 256, 0, stream>>>(out2, W3T, h3, a3s, a3d,
                                                       al_s3, al_d3, N, 64);
  attn_h1_kernel<<<(N + 3) / 4, 256, 0, stream>>>(indptr, csr, al_s3, al_d3, h3,
                                                  b3, out3, N);

  // Pool + FC (no atomics)
  pool_fc_kernel<<<64, 256, 0, stream>>>(out3, batch, N, fcW, fcb, out);
}

// Round 8
// 405.808 us; speedup vs baseline: 1.1112x; 1.0180x over previous
//
#include <hip/hip_runtime.h>
#include <hip/hip_bf16.h>
#include <cstdint>

#define NEG_SLOPE 0.2f

typedef __attribute__((ext_vector_type(8))) short bf16x8;
typedef __attribute__((ext_vector_type(4))) float f32x4;
typedef __attribute__((ext_vector_type(2))) float f32x2;

__device__ __forceinline__ float bf2f(uint32_t u) {
  union { float f; uint32_t i; } v;
  v.i = u << 16;
  return v.f;
}
__device__ __forceinline__ float lo16(uint32_t u) {
  union { float f; uint32_t i; } v;
  v.i = u << 16;
  return v.f;
}
__device__ __forceinline__ float hi16(uint32_t u) {
  union { float f; uint32_t i; } v;
  v.i = u & 0xffff0000u;
  return v.f;
}
__device__ __forceinline__ ushort f2bf(float f) {
  union { float f; uint32_t i; } v;
  v.f = f;
  uint32_t r = v.i + 0x7FFF + ((v.i >> 16) & 1);  // round-nearest-even
  return (ushort)(r >> 16);
}

// ---------------------------------------------------------------------------
// prep: cast x -> bf16, transpose+cast W1/W2/W3, CSR count pass,
// and fold attention vectors through W1:  at_s[k][h] = sum_c W1[k][h*64+c]*a1s[h][c]
// ---------------------------------------------------------------------------
__global__ void prep_kernel(const float4* __restrict__ x,
                            uint2* __restrict__ x_bf, int n_x4,
                            const float* __restrict__ W1,
                            ushort* __restrict__ W1T,
                            const float* __restrict__ W2,
                            ushort* __restrict__ W2T,
                            const float* __restrict__ W3,
                            ushort* __restrict__ W3T,
                            const int* __restrict__ dst, int* __restrict__ cnt,
                            const float* __restrict__ a1s,
                            const float* __restrict__ a1d,
                            float* __restrict__ at_s, float* __restrict__ at_d,
                            int E) {
  int i = blockIdx.x * 256 + threadIdx.x;
  const int r0 = n_x4;
  const int r1 = r0 + 512 * 128;
  const int r2 = r1 + 64 * 512;
  const int r3 = r2 + 64 * 64;
  const int r4 = r3 + E;
  const int r5 = r4 + 1024;
  const int r6 = r5 + 1024;
  if (i < r0) {
    float4 v = x[i];
    uint2 o;
    o.x = (uint32_t)f2bf(v.x) | ((uint32_t)f2bf(v.y) << 16);
    o.y = (uint32_t)f2bf(v.z) | ((uint32_t)f2bf(v.w) << 16);
    x_bf[i] = o;
  } else if (i < r1) {
    int idx = i - r0;
    int n = idx >> 7, k = idx & 127;
    W1T[idx] = f2bf(W1[(size_t)k * 512 + n]);
  } else if (i < r2) {
    int idx = i - r1;
    int n = idx >> 9, k = idx & 511;
    W2T[idx] = f2bf(W2[(size_t)k * 64 + n]);
  } else if (i < r3) {
    int idx = i - r2;
    int n = idx >> 6, k = idx & 63;
    W3T[idx] = f2bf(W3[(size_t)k * 64 + n]);
  } else if (i < r4) {
    atomicAdd(&cnt[dst[i - r3]], 1);
  } else if (i < r5) {
    int idx = i - r4;  // k*8 + h
    int k = idx >> 3, h = idx & 7;
    float a = 0.f;
    for (int c = 0; c < 64; ++c)
      a = fmaf(W1[(size_t)k * 512 + h * 64 + c], a1s[h * 64 + c], a);
    at_s[idx] = a;
  } else if (i < r6) {
    int idx = i - r5;
    int k = idx >> 3, h = idx & 7;
    float a = 0.f;
    for (int c = 0; c < 64; ++c)
      a = fmaf(W1[(size_t)k * 512 + h * 64 + c], a1d[h * 64 + c], a);
    at_d[idx] = a;
  }
}

// ---------------------------------------------------------------------------
// Layer-1 al from x directly: al_s[n][h] = x[n] . at_s[:,h]  (K=128, 16 outs)
// ---------------------------------------------------------------------------
__global__ __launch_bounds__(256) void algemm_kernel(
    const ushort* __restrict__ x_bf, const float* __restrict__ at_s,
    const float* __restrict__ at_d, float* __restrict__ al_s,
    float* __restrict__ al_d, int Nn) {
  const int n = blockIdx.x * 256 + threadIdx.x;
  if (n >= Nn) return;
  float as8[8] = {}, ad8[8] = {};
  const ushort* xp = x_bf + (size_t)n * 128;
  for (int k0 = 0; k0 < 128; k0 += 8) {
    const uint4 xw = *(const uint4*)(xp + k0);
    const uint32_t ww0 = xw.x, ww1 = xw.y, ww2 = xw.z, ww3 = xw.w;
    float xv[8];
    xv[0] = lo16(ww0); xv[1] = hi16(ww0);
    xv[2] = lo16(ww1); xv[3] = hi16(ww1);
    xv[4] = lo16(ww2); xv[5] = hi16(ww2);
    xv[6] = lo16(ww3); xv[7] = hi16(ww3);
#pragma unroll
    for (int t = 0; t < 8; ++t) {
      const int k = k0 + t;
#pragma unroll
      for (int h = 0; h < 8; ++h) {
        as8[h] = fmaf(xv[t], at_s[k * 8 + h], as8[h]);
        ad8[h] = fmaf(xv[t], at_d[k * 8 + h], ad8[h]);
      }
    }
  }
  float4* ps = (float4*)(al_s + (size_t)n * 8);
  ps[0] = make_float4(as8[0], as8[1], as8[2], as8[3]);
  ps[1] = make_float4(as8[4], as8[5], as8[6], as8[7]);
  float4* pd = (float4*)(al_d + (size_t)n * 8);
  pd[0] = make_float4(ad8[0], ad8[1], ad8[2], ad8[3]);
  pd[1] = make_float4(ad8[4], ad8[5], ad8[6], ad8[7]);
}

// ---------------------------------------------------------------------------
// GEMM (N=64) + fused al (H=1): C[M,64] = A[M,K] @ BT[64,K].  (layer 3)
// ---------------------------------------------------------------------------
__global__ __launch_bounds__(256) void gemm_n64_al(
    const ushort* __restrict__ A, const ushort* __restrict__ BT,
    ushort* __restrict__ C, const float* __restrict__ asrc,
    const float* __restrict__ adst, float* __restrict__ al_s,
    float* __restrict__ al_d, int M, int K) {
  const int wave = threadIdx.x >> 6;
  const int lane = threadIdx.x & 63;
  const int rt = blockIdx.y * 4 + wave;
  const int r0 = rt * 16;
  if (r0 >= M) return;
  const int l15 = lane & 15, q = lane >> 4;
  const ushort* Ap = A + (size_t)(r0 + l15) * K + q * 8;
  f32x4 acc[4] = {};
  for (int k0 = 0; k0 < K; k0 += 32) {
    bf16x8 a = *(const bf16x8*)(Ap + k0);
#pragma unroll
    for (int j = 0; j < 4; ++j) {
      const bf16x8 b =
          *(const bf16x8*)(BT + (size_t)(j * 16 + l15) * K + q * 8 + k0);
      acc[j] = __builtin_amdgcn_mfma_f32_16x16x32_bf16(a, b, acc[j], 0, 0, 0);
    }
  }
#pragma unroll
  for (int j = 0; j < 4; ++j)
#pragma unroll
    for (int r = 0; r < 4; ++r) {
      int row = r0 + q * 4 + r;
      C[(size_t)row * 64 + j * 16 + l15] = f2bf(acc[j][r]);
    }
  float als_p[4] = {0.f, 0.f, 0.f, 0.f};
  float ald_p[4] = {0.f, 0.f, 0.f, 0.f};
#pragma unroll
  for (int j = 0; j < 4; ++j) {
    float wsc = asrc[j * 16 + l15];
    float wdc = adst[j * 16 + l15];
#pragma unroll
    for (int r = 0; r < 4; ++r) {
      als_p[r] = fmaf(acc[j][r], wsc, als_p[r]);
      ald_p[r] = fmaf(acc[j][r], wdc, ald_p[r]);
    }
  }
#pragma unroll
  for (int r = 0; r < 4; ++r) {
    float vs = als_p[r], vd = ald_p[r];
#pragma unroll
    for (int off = 1; off < 16; off <<= 1) {
      vs += __shfl_xor(vs, off);
      vd += __shfl_xor(vd, off);
    }
    if (l15 == 0) {
      int row = r0 + q * 4 + r;
      al_s[row] = vs;
      al_d[row] = vd;
    }
  }
}

// ---------------------------------------------------------------------------
// FUSED layers 1b+2a, 64-row tile, register-blocked (round-7 version).
// ---------------------------------------------------------------------------
__global__ __launch_bounds__(256) void gemm12_kernel(
    const ushort* __restrict__ agg, const ushort* __restrict__ W1T,
    const float* __restrict__ b1, const ushort* __restrict__ W2T,
    const float* __restrict__ a2s, const float* __restrict__ a2d,
    ushort* __restrict__ h2, float* __restrict__ al_s,
    float* __restrict__ al_d, int M) {
  __shared__ ushort o1t[64][520];  // padded stride (1040 B)
  __shared__ float als_sm[4][64];
  __shared__ float ald_sm[4][64];
  const int w = threadIdx.x >> 6;
  const int lane = threadIdx.x & 63;
  const int l15 = lane & 15, q = lane >> 4;
  const int r0 = blockIdx.x * 64;

  int rrd[4];
#pragma unroll
  for (int rt = 0; rt < 4; ++rt) rrd[rt] = min(r0 + rt * 16 + l15, M - 1);

  // ---- stage 1: two heads per wave, one at a time
#pragma unroll
  for (int hi = 0; hi < 2; ++hi) {
    const int hd = w * 2 + hi;
    f32x4 acc[4][4] = {};
    for (int k0 = 0; k0 < 128; k0 += 32) {
      bf16x8 wf[4];
#pragma unroll
      for (int j = 0; j < 4; ++j)
        wf[j] = *(const bf16x8*)(W1T +
                                 (size_t)(hd * 64 + j * 16 + l15) * 128 +
                                 q * 8 + k0);
      bf16x8 af[4];
#pragma unroll
      for (int rt = 0; rt < 4; ++rt)
        af[rt] = *(const bf16x8*)(agg + ((size_t)hd * M + rrd[rt]) * 128 +
                                  q * 8 + k0);
#pragma unroll
      for (int rt = 0; rt < 4; ++rt)
#pragma unroll
        for (int j = 0; j < 4; ++j)
          acc[rt][j] = __builtin_amdgcn_mfma_f32_16x16x32_bf16(
              af[rt], wf[j], acc[rt][j], 0, 0, 0);
    }
#pragma unroll
    for (int j = 0; j < 4; ++j) {
      const int col = hd * 64 + j * 16 + l15;
      const float bb = b1[col];
#pragma unroll
      for (int rt = 0; rt < 4; ++rt)
#pragma unroll
        for (int r = 0; r < 4; ++r) {
          float v = acc[rt][j][r] + bb;
          v = (v > 0.f) ? v : __expf(v) - 1.f;
          o1t[rt * 16 + q * 4 + r][col] = f2bf(v);
        }
    }
  }
  __syncthreads();

  // ---- stage 2: wave w computes h2 cols w*16..w*16+15, K=512 from LDS
  f32x4 acc2[4] = {};
  for (int k0 = 0; k0 < 512; k0 += 32) {
    const bf16x8 b = *(const bf16x8*)(W2T +
                                      (size_t)(w * 16 + l15) * 512 + q * 8 +
                                      k0);
#pragma unroll
    for (int rt = 0; rt < 4; ++rt) {
      const bf16x8 a = *(const bf16x8*)(&o1t[rt * 16 + l15][k0 + q * 8]);
      acc2[rt] = __builtin_amdgcn_mfma_f32_16x16x32_bf16(a, b, acc2[rt], 0, 0, 0);
    }
  }
  const float wsc = a2s[w * 16 + l15];
  const float wdc = a2d[w * 16 + l15];
#pragma unroll
  for (int rt = 0; rt < 4; ++rt)
#pragma unroll
    for (int r = 0; r < 4; ++r) {
      const int row = r0 + rt * 16 + q * 4 + r;
      if (row < M) h2[(size_t)row * 64 + w * 16 + l15] = f2bf(acc2[rt][r]);
      float vs = acc2[rt][r] * wsc, vd = acc2[rt][r] * wdc;
#pragma unroll
      for (int off = 1; off < 16; off <<= 1) {
        vs += __shfl_xor(vs, off);
        vd += __shfl_xor(vd, off);
      }
      if (l15 == 0) {
        als_sm[w][rt * 16 + q * 4 + r] = vs;
        ald_sm[w][rt * 16 + q * 4 + r] = vd;
      }
    }
  __syncthreads();
  if (threadIdx.x < 64) {
    const int row = r0 + threadIdx.x;
    if (row < M) {
      const int t = threadIdx.x;
      al_s[row] = als_sm[0][t] + als_sm[1][t] + als_sm[2][t] + als_sm[3][t];
      al_d[row] = ald_sm[0][t] + ald_sm[1][t] + ald_sm[2][t] + ald_sm[3][t];
    }
  }
}

// ---------------------------------------------------------------------------
// CSR: per-block inclusive scan (block sums to bsum)
// ---------------------------------------------------------------------------
__global__ void scan_block(const int* __restrict__ in, int* __restrict__ out,
                           int* __restrict__ bsum, int n) {
  __shared__ int sm[256];
  int gid = blockIdx.x * 256 + threadIdx.x;
  int v = (gid < n) ? in[gid] : 0;
  sm[threadIdx.x] = v;
  __syncthreads();
  for (int off = 1; off < 256; off <<= 1) {
    int t = (threadIdx.x >= off) ? sm[threadIdx.x - off] : 0;
    __syncthreads();
    sm[threadIdx.x] += t;
    __syncthreads();
  }
  if (gid < n) out[gid] = sm[threadIdx.x];
  if (threadIdx.x == 255) bsum[blockIdx.x] = sm[255];
}

__global__ void scan_final2(const int* __restrict__ inc,
                            const int* __restrict__ bsum,
                            int* __restrict__ indptr, int* __restrict__ fill,
                            int n) {
  __shared__ int sm[256];
  const int t = threadIdx.x, bx = blockIdx.x;
  sm[t] = (t < bx) ? bsum[t] : 0;  // gridDim <= 256
  __syncthreads();
  for (int off = 128; off; off >>= 1) {
    if (t < off) sm[t] += sm[t + off];
    __syncthreads();
  }
  const int prefix = sm[0];
  int gid = bx * 256 + t;
  if (gid < n) {
    int val = inc[gid] + prefix;
    indptr[gid + 1] = val;
    fill[gid + 1] = val;
  }
  if (gid == 0) {
    indptr[0] = 0;
    fill[0] = 0;
  }
}

__global__ void scatter_kernel(const int* __restrict__ src,
                               const int* __restrict__ dst,
                               int* __restrict__ fill,
                               int* __restrict__ csr_src, int E) {
  int e = blockIdx.x * 256 + threadIdx.x;
  if (e < E) {
    int pos = atomicAdd(&fill[dst[e]], 1);
    csr_src[pos] = src[e];
  }
}

// ---------------------------------------------------------------------------
// Layer-1 attention in x-space, cooperative-row layout + 8-edge batched loads
// + packed f32x2 FMA (v_pk_fma_f32): 8 pk-fma per edge instead of 16 scalar.
// Output agg is HEAD-MAJOR [8][N][128].
// ---------------------------------------------------------------------------
__global__ __launch_bounds__(256) void attn1x_kernel(
    const int* __restrict__ indptr, const int* __restrict__ csr_src,
    const float* __restrict__ al_s, const float* __restrict__ al_d,
    const ushort* __restrict__ x_bf, ushort* __restrict__ agg, int Nn) {
  __shared__ float u_sm[4][64 * 8];
  __shared__ int s_sm[4][64];
  const int wv = threadIdx.x >> 6;
  const int l = threadIdx.x & 63;
  const int w = (blockIdx.x * 256 + threadIdx.x) >> 6;
  if (w >= Nn) return;
  const int d = w;
  const int start = indptr[d];
  const int deg = indptr[d + 1] - start;
  const int total = deg + 1;  // + self loop
  const float4 ad0 = *(const float4*)(al_d + (size_t)d * 8);
  const float4 ad1 = *(const float4*)(al_d + (size_t)d * 8 + 4);
  const ushort* xcol = x_bf + l * 2;  // channel pair (2l, 2l+1)

  f32x2 accv[8] = {};  // per-head accum: (.x = ch 2l, .y = ch 2l+1)
  float den8[8] = {};
  float* usm = u_sm[wv];
  int* ssm = s_sm[wv];

  for (int e0 = 0; e0 < total; e0 += 64) {
    // ---- stage A: lane-parallel (s, u[8]) for this 64-edge block
    const int e = e0 + l;
    int s_l = d;
    float u8[8] = {};
    if (e < total) {
      s_l = (e < deg) ? csr_src[start + e] : d;
      const float4 s0 = *(const float4*)(al_s + (size_t)s_l * 8);
      const float4 s1 = *(const float4*)(al_s + (size_t)s_l * 8 + 4);
      float vv[8];
      vv[0] = s0.x + ad0.x; vv[1] = s0.y + ad0.y;
      vv[2] = s0.z + ad0.z; vv[3] = s0.w + ad0.w;
      vv[4] = s1.x + ad1.x; vv[5] = s1.y + ad1.y;
      vv[6] = s1.z + ad1.z; vv[7] = s1.w + ad1.w;
#pragma unroll
      for (int k = 0; k < 8; ++k) {
        float v = fmaxf(vv[k], NEG_SLOPE * vv[k]);
        u8[k] = __expf(v);
        den8[k] += u8[k];
      }
    }
    ssm[l] = s_l;
    ((float4*)(usm + l * 8))[0] = make_float4(u8[0], u8[1], u8[2], u8[3]);
    ((float4*)(usm + l * 8))[1] = make_float4(u8[4], u8[5], u8[6], u8[7]);

    const int ne = min(64, total - e0);
    int j = 0;
    for (; j + 8 <= ne; j += 8) {
      const int4 sa = *(const int4*)(ssm + j);
      const int4 sb = *(const int4*)(ssm + j + 4);
      const int sv[8] = {sa.x, sa.y, sa.z, sa.w, sb.x, sb.y, sb.z, sb.w};
      uint32_t wx[8];
#pragma unroll
      for (int t = 0; t < 8; ++t)
        wx[t] = *(const uint32_t*)(xcol + (size_t)sv[t] * 128);
#pragma unroll
      for (int t = 0; t < 8; ++t) {
        const float4 ua = *((const float4*)(usm + (j + t) * 8));
        const float4 ub = *((const float4*)(usm + (j + t) * 8) + 1);
        const f32x2 xv = {lo16(wx[t]), hi16(wx[t])};
        accv[0] = __builtin_elementwise_fma((f32x2){ua.x, ua.x}, xv, accv[0]);
        accv[1] = __builtin_elementwise_fma((f32x2){ua.y, ua.y}, xv, accv[1]);
        accv[2] = __builtin_elementwise_fma((f32x2){ua.z, ua.z}, xv, accv[2]);
        accv[3] = __builtin_elementwise_fma((f32x2){ua.w, ua.w}, xv, accv[3]);
        accv[4] = __builtin_elementwise_fma((f32x2){ub.x, ub.x}, xv, accv[4]);
        accv[5] = __builtin_elementwise_fma((f32x2){ub.y, ub.y}, xv, accv[5]);
        accv[6] = __builtin_elementwise_fma((f32x2){ub.z, ub.z}, xv, accv[6]);
        accv[7] = __builtin_elementwise_fma((f32x2){ub.w, ub.w}, xv, accv[7]);
      }
    }
    for (; j < ne; ++j) {
      const int s = ssm[j];
      const float4 ua = *((const float4*)(usm + j * 8));
      const float4 ub = *((const float4*)(usm + j * 8) + 1);
      const uint32_t wx = *(const uint32_t*)(xcol + (size_t)s * 128);
      const f32x2 xv = {lo16(wx), hi16(wx)};
      accv[0] = __builtin_elementwise_fma((f32x2){ua.x, ua.x}, xv, accv[0]);
      accv[1] = __builtin_elementwise_fma((f32x2){ua.y, ua.y}, xv, accv[1]);
      accv[2] = __builtin_elementwise_fma((f32x2){ua.z, ua.z}, xv, accv[2]);
      accv[3] = __builtin_elementwise_fma((f32x2){ua.w, ua.w}, xv, accv[3]);
      accv[4] = __builtin_elementwise_fma((f32x2){ub.x, ub.x}, xv, accv[4]);
      accv[5] = __builtin_elementwise_fma((f32x2){ub.y, ub.y}, xv, accv[5]);
      accv[6] = __builtin_elementwise_fma((f32x2){ub.z, ub.z}, xv, accv[6]);
      accv[7] = __builtin_elementwise_fma((f32x2){ub.w, ub.w}, xv, accv[7]);
    }
  }
  // den: each lane held distinct edges (padded u=0) -> full 64-lane reduce
#pragma unroll
  for (int k = 0; k < 8; ++k) {
#pragma unroll
    for (int off = 1; off < 64; off <<= 1) den8[k] += __shfl_xor(den8[k], off);
  }
  // write agg head-major: for head h, 64 lanes write 256 B contiguous
#pragma unroll
  for (int h = 0; h < 8; ++h) {
    const float inv = 1.f / den8[h];
    const uint32_t st = (uint32_t)f2bf(accv[h].x * inv) |
                        ((uint32_t)f2bf(accv[h].y * inv) << 16);
    *(uint32_t*)(agg + ((size_t)h * Nn + d) * 128 + l * 2) = st;
  }
}

// ---------------------------------------------------------------------------
// Attention H=1, C=64 (layers 2 and 3): one wave per dst node.
// Packed f32x2 FMA: 4 pk-fma per 8-ch chunk instead of 8 scalar.
// ---------------------------------------------------------------------------
__global__ __launch_bounds__(256) void attn_h1_kernel(
    const int* __restrict__ indptr, const int* __restrict__ csr_src,
    const float* __restrict__ al_s, const float* __restrict__ al_d,
    const ushort* __restrict__ hin, const float* __restrict__ bias,
    ushort* __restrict__ outp, int Nn) {
  const int w = (blockIdx.x * 256 + threadIdx.x) >> 6;
  const int l = threadIdx.x & 63;
  if (w >= Nn) return;
  const int d = w;
  const int start = indptr[d];
  const int deg = indptr[d + 1] - start;
  const int total = deg + 1;
  const int t = l >> 3;  // edge slot within chunk
  const int c8 = l & 7;  // channel block (8 ch)
  const float ald = al_d[d];
  const ushort* hl = hin + c8 * 8;

  f32x2 av[4] = {};
  float den = 0.f;

  for (int e0 = 0; e0 < total; e0 += 64) {
    // stage A: all 64 lanes compute s,u for this 64-edge block
    const int e = e0 + l;
    int s_l = d;
    float u_l = 0.f;
    if (e < total) {
      s_l = (e < deg) ? csr_src[start + e] : d;
      float v = al_s[s_l] + ald;
      v = fmaxf(v, NEG_SLOPE * v);
      u_l = __expf(v);
      den += u_l;
    }
    const int ne = min(64, total - e0);
    // 2-deep pipelined chunk loop (8 edges per chunk)
    int su0 = __shfl(s_l, t);
    float uv0 = __shfl(u_l, t);
    uint4 h0 = *(const uint4*)(hl + (size_t)su0 * 64);
    int j = 0;
    for (; j + 8 < ne; j += 8) {
      const int su1 = __shfl(s_l, j + 8 + t);
      const float uv1 = __shfl(u_l, j + 8 + t);
      const uint4 h1v = *(const uint4*)(hl + (size_t)su1 * 64);
      const f32x2 uu = {uv0, uv0};
      av[0] = __builtin_elementwise_fma(uu, (f32x2){lo16(h0.x), hi16(h0.x)}, av[0]);
      av[1] = __builtin_elementwise_fma(uu, (f32x2){lo16(h0.y), hi16(h0.y)}, av[1]);
      av[2] = __builtin_elementwise_fma(uu, (f32x2){lo16(h0.z), hi16(h0.z)}, av[2]);
      av[3] = __builtin_elementwise_fma(uu, (f32x2){lo16(h0.w), hi16(h0.w)}, av[3]);
      uv0 = uv1;
      h0 = h1v;
    }
    const f32x2 uu = {uv0, uv0};
    av[0] = __builtin_elementwise_fma(uu, (f32x2){lo16(h0.x), hi16(h0.x)}, av[0]);
    av[1] = __builtin_elementwise_fma(uu, (f32x2){lo16(h0.y), hi16(h0.y)}, av[1]);
    av[2] = __builtin_elementwise_fma(uu, (f32x2){lo16(h0.z), hi16(h0.z)}, av[2]);
    av[3] = __builtin_elementwise_fma(uu, (f32x2){lo16(h0.w), hi16(h0.w)}, av[3]);
  }
  float acc[8];
#pragma unroll
  for (int k = 0; k < 4; ++k) {
    acc[2 * k] = av[k].x;
    acc[2 * k + 1] = av[k].y;
  }
  // reduce acc across the 8 edge slots (bits 3..5); c8 preserved
#pragma unroll
  for (int k = 0; k < 8; ++k) {
    acc[k] += __shfl_xor(acc[k], 8);
    acc[k] += __shfl_xor(acc[k], 16);
    acc[k] += __shfl_xor(acc[k], 32);
  }
  // den: each lane held distinct edges -> full 64-lane reduce
#pragma unroll
  for (int off = 32; off; off >>= 1) den += __shfl_xor(den, off);
  const float inv = 1.f / den;
  if (l < 8) {  // lanes 0..7: t==0, c8==l
    float o[8];
#pragma unroll
    for (int k = 0; k < 8; ++k) {
      float v = acc[k] * inv + bias[l * 8 + k];
      o[k] = (v > 0.f) ? v : __expf(v) - 1.f;
    }
    uint4 st;
    st.x = (uint32_t)f2bf(o[0]) | ((uint32_t)f2bf(o[1]) << 16);
    st.y = (uint32_t)f2bf(o[2]) | ((uint32_t)f2bf(o[3]) << 16);
    st.z = (uint32_t)f2bf(o[4]) | ((uint32_t)f2bf(o[5]) << 16);
    st.w = (uint32_t)f2bf(o[6]) | ((uint32_t)f2bf(o[7]) << 16);
    *(uint4*)(outp + (size_t)d * 64 + l * 8) = st;
  }
}

// ---------------------------------------------------------------------------
// Pool + FC: one block per graph. Segment-mean over out3 (bf16 N x 64),
// then pooled @ fcW + fcb. No global atomics.
// ---------------------------------------------------------------------------
__global__ __launch_bounds__(256) void pool_fc_kernel(
    const ushort* __restrict__ out3, const int* __restrict__ batch, int Nn,
    const float* __restrict__ fcW, const float* __restrict__ fcb,
    float* __restrict__ out) {
  __shared__ int bnds[2];
  __shared__ float sm[4 * 64];
  __shared__ float pm[64];
  const int tid = threadIdx.x;
  const int g = blockIdx.x;
  if (tid < 2) {
    int target = g + tid;
    int lo = 0, hi = Nn;
    while (lo < hi) {
      int mid = (lo + hi) >> 1;
      if (batch[mid] < target) lo = mid + 1; else hi = mid;
    }
    bnds[tid] = lo;
  }
  __syncthreads();
  const int lb = bnds[0], ub = bnds[1];

  const int ro = tid >> 3, c8 = tid & 7;
  float acc[8] = {0.f, 0.f, 0.f, 0.f, 0.f, 0.f, 0.f, 0.f};
  for (int r = lb + ro; r < ub; r += 32) {
    const uint4 hh4 = *(const uint4*)(out3 + (size_t)r * 64 + c8 * 8);
    acc[0] += lo16(hh4.x);
    acc[1] += hi16(hh4.x);
    acc[2] += lo16(hh4.y);
    acc[3] += hi16(hh4.y);
    acc[4] += lo16(hh4.z);
    acc[5] += hi16(hh4.z);
    acc[6] += lo16(hh4.w);
    acc[7] += hi16(hh4.w);
  }
#pragma unroll
  for (int k = 0; k < 8; ++k) {
    acc[k] += __shfl_xor(acc[k], 8);
    acc[k] += __shfl_xor(acc[k], 16);
    acc[k] += __shfl_xor(acc[k], 32);
  }
  const int wv = tid >> 6, ll = tid & 63;
  if (ll < 8) {
#pragma unroll
    for (int k = 0; k < 8; ++k) sm[wv * 64 + ll * 8 + k] = acc[k];
  }
  __syncthreads();
  if (tid < 64) {
    float tot = sm[tid] + sm[64 + tid] + sm[128 + tid] + sm[192 + tid];
    pm[tid] = tot / fmaxf((float)(ub - lb), 1.f);
  }
  __syncthreads();
  if (tid < 10) {
    float a = fcb[tid];
    for (int c = 0; c < 64; ++c) a = fmaf(pm[c], fcW[c * 10 + tid], a);
    out[g * 10 + tid] = a;
  }
}

// ---------------------------------------------------------------------------
extern "C" void kernel_launch(void* const* d_in, const int* in_sizes, int n_in,
                              void* d_out, int out_size, void* d_ws,
                              size_t ws_size, hipStream_t stream) {
  const float* x = (const float*)d_in[0];
  const int* ei = (const int*)d_in[1];
  const int* batch = (const int*)d_in[2];
  const float* W1 = (const float*)d_in[3];
  const float* a1s = (const float*)d_in[4];
  const float* a1d = (const float*)d_in[5];
  const float* b1 = (const float*)d_in[6];
  const float* W2 = (const float*)d_in[7];
  const float* a2s = (const float*)d_in[8];
  const float* a2d = (const float*)d_in[9];
  const float* b2 = (const float*)d_in[10];
  const float* W3 = (const float*)d_in[11];
  const float* a3s = (const float*)d_in[12];
  const float* a3d = (const float*)d_in[13];
  const float* b3 = (const float*)d_in[14];
  const float* fcW = (const float*)d_in[15];
  const float* fcb = (const float*)d_in[16];
  float* out = (float*)d_out;

  const int N = in_sizes[0] / 128;  // 50000
  const int E = in_sizes[1] / 2;    // 800000
  const int* srcp = ei;
  const int* dstp = ei + E;

  // --- workspace layout ---
  char* ws = (char*)d_ws;
  size_t off = 0;
  auto alloc = [&](size_t bytes) -> void* {
    off = (off + 255) & ~(size_t)255;
    void* p = ws + off;
    off += bytes;
    return p;
  };
  ushort* x_bf = (ushort*)alloc((size_t)N * 128 * 2);
  ushort* W1T = (ushort*)alloc(512 * 128 * 2);
  ushort* W2T = (ushort*)alloc(64 * 512 * 2);
  ushort* W3T = (ushort*)alloc(64 * 64 * 2);
  float* at_s = (float*)alloc(128 * 8 * 4);
  float* at_d = (float*)alloc(128 * 8 * 4);
  ushort* agg = (ushort*)alloc((size_t)N * 1024 * 2);   // head-major [8][N][128]
  ushort* hreg = (ushort*)alloc((size_t)4 * N * 64 * 2);  // h2/out2/h3/out3
  float* al_s1 = (float*)alloc((size_t)N * 8 * 4);
  float* al_d1 = (float*)alloc((size_t)N * 8 * 4);
  float* al_s2 = (float*)alloc((size_t)N * 4);
  float* al_d2 = (float*)alloc((size_t)N * 4);
  float* al_s3 = (float*)alloc((size_t)N * 4);
  float* al_d3 = (float*)alloc((size_t)N * 4);
  int* cnt = (int*)alloc((size_t)N * 4);
  int* fill = (int*)alloc((size_t)(N + 1) * 4);
  int* indptr = (int*)alloc((size_t)(N + 1) * 4);
  int* csr = (int*)alloc((size_t)E * 4);
  int* incbuf = (int*)alloc((size_t)N * 4);
  int* bsum = (int*)alloc(1024 * 4);

  ushort* h2 = hreg;
  ushort* out2 = hreg + (size_t)N * 64;
  ushort* h3 = hreg + (size_t)2 * N * 64;
  ushort* out3 = hreg + (size_t)3 * N * 64;

  hipMemsetAsync(cnt, 0, (size_t)N * 4, stream);

  const int scan_blocks = (N + 255) / 256;  // 196 (<256 required)
  const int row_blocks = (N / 16 + 3) / 4;
  const int tile_blocks = (N + 63) / 64;  // 782

  // prep: x cast + weight transposes + CSR count + at (W1^T a) fold
  const int n_x4 = N * 128 / 4;
  const int prep_total = n_x4 + 512 * 128 + 64 * 512 + 64 * 64 + E + 2048;
  prep_kernel<<<(prep_total + 255) / 256, 256, 0, stream>>>(
      (const float4*)x, (uint2*)x_bf, n_x4, W1, W1T, W2, W2T, W3, W3T, dstp,
      cnt, a1s, a1d, at_s, at_d, E);

  // layer-1 al from x directly
  algemm_kernel<<<(N + 255) / 256, 256, 0, stream>>>(x_bf, at_s, at_d, al_s1,
                                                     al_d1, N);
  // CSR build
  scan_block<<<scan_blocks, 256, 0, stream>>>(cnt, incbuf, bsum, N);
  scan_final2<<<scan_blocks, 256, 0, stream>>>(incbuf, bsum, indptr, fill, N);
  scatter_kernel<<<(E + 255) / 256, 256, 0, stream>>>(srcp, dstp, fill, csr, E);

  // Layer 1: attention in x-space (256 B rows), head-major agg
  attn1x_kernel<<<(N + 3) / 4, 256, 0, stream>>>(indptr, csr, al_s1, al_d1,
                                                 x_bf, agg, N);
  // Fused: out1 = ELU(agg@W1+b1) kept in LDS -> h2 = out1@W2 (+al2)
  gemm12_kernel<<<tile_blocks, 256, 0, stream>>>(agg, W1T, b1, W2T, a2s, a2d,
                                                 h2, al_s2, al_d2, N);
  attn_h1_kernel<<<(N + 3) / 4, 256, 0, stream>>>(indptr, csr, al_s2, al_d2, h2,
                                                  b2, out2, N);

  // Layer 3
  gemm_n64_al<<<dim3(1, row_blocks), 256, 0, stream>>>(out2, W3T, h3, a3s, a3d,
                                                       al_s3, al_d3, N, 64);
  attn_h1_kernel<<<(N + 3) / 4, 256, 0, stream>>>(indptr, csr, al_s3, al_d3, h3,
                                                  b3, out3, N);

  // Pool + FC (no atomics)
  pool_fc_kernel<<<64, 256, 0, stream>>>(out3, batch, N, fcW, fcb, out);
}